// Round 1
// baseline (1953.339 us; speedup 1.0000x reference)
//
#include <hip/hip_runtime.h>
#include <hip/hip_bf16.h>

#define TOPK 15

// ---------- helpers ----------
__device__ __forceinline__ float iou_xyxy(float ax1, float ay1, float ax2, float ay2,
                                          float bx1, float by1, float bx2, float by2) {
    float ltx = fmaxf(ax1, bx1), lty = fmaxf(ay1, by1);
    float rbx = fminf(ax2, bx2), rby = fminf(ay2, by2);
    float w = fmaxf(rbx - ltx, 0.0f), h = fmaxf(rby - lty, 0.0f);
    float inter = w * h;
    float areaA = (ax2 - ax1) * (ay2 - ay1);
    float areaB = (bx2 - bx1) * (by2 - by1);
    return inter / (areaA + areaB - inter);
}

// ---------- K0: zero accumulators ----------
__global__ void k_zero(double* accC, double* accL, double* accR, unsigned int* posCount) {
    if (threadIdx.x == 0) {
        *accC = 0.0; *accL = 0.0; *accR = 0.0; *posCount = 0u;
    }
}

// ---------- K1: reg matrix  F[n][o][p] = filtered jaccard(truths, decode(loc)) ----------
__global__ void k_reg_matrix(const float* __restrict__ loc, const float* __restrict__ priors,
                             const float* __restrict__ truths, float* __restrict__ F,
                             int P) {
    int n = blockIdx.y;
    int p = blockIdx.x * blockDim.x + threadIdx.x;
    __shared__ float tr[64];
    if (threadIdx.x < 64) tr[threadIdx.x] = truths[n * 64 + threadIdx.x];
    __syncthreads();
    if (p >= P) return;
    float4 pr = *(const float4*)(priors + (size_t)p * 4);
    float4 l  = *(const float4*)(loc + ((size_t)n * P + p) * 4);
    // decode: cxcy = pr.cxcy + l.xy*0.1*pr.wh ; wh = pr.wh*exp(l.zw*0.2)
    float cx = pr.x + l.x * 0.1f * pr.z;
    float cy = pr.y + l.y * 0.1f * pr.w;
    float w  = pr.z * expf(l.z * 0.2f);
    float h  = pr.w * expf(l.w * 0.2f);
    float bx1 = cx - w * 0.5f, by1 = cy - h * 0.5f;
    float bx2 = cx + w * 0.5f, by2 = cy + h * 0.5f;
    float v[16];
    float m = -1.0f;
    #pragma unroll
    for (int o = 0; o < 16; o++) {
        v[o] = iou_xyxy(tr[o * 4], tr[o * 4 + 1], tr[o * 4 + 2], tr[o * 4 + 3],
                        bx1, by1, bx2, by2);
        m = fmaxf(m, v[o]);
    }
    size_t base = ((size_t)n * 16) * P + p;
    #pragma unroll
    for (int o = 0; o < 16; o++) {
        F[base + (size_t)o * P] = (v[o] == m) ? v[o] : 0.0f;
    }
}

// ---------- K2/K5: per-row top-15 + boost (exact jax.lax.top_k semantics) ----------
// one block per row (n*16+o). 15 rounds of block argmax (value desc, index asc).
__global__ void k_topk_boost(float* __restrict__ F, int P) {
    int row = blockIdx.x;
    float* R = F + (size_t)row * P;
    __shared__ float sv[256];
    __shared__ int   si[256];
    __shared__ int   selIdx[TOPK];
    __shared__ float selVal[TOPK];
    __shared__ int   snum;
    int tid = threadIdx.x;

    for (int k = 0; k < TOPK; k++) {
        float bv = -1.0f;           // all values >= 0
        int   bi = 0x7FFFFFFF;
        for (int p = tid; p < P; p += 256) {
            bool skip = false;
            for (int j = 0; j < k; j++) if (selIdx[j] == p) skip = true;
            if (skip) continue;
            float v = R[p];
            if (v > bv || (v == bv && p < bi)) { bv = v; bi = p; }
        }
        sv[tid] = bv; si[tid] = bi;
        __syncthreads();
        for (int s = 128; s > 0; s >>= 1) {
            if (tid < s) {
                float v2 = sv[tid + s]; int i2 = si[tid + s];
                if (v2 > sv[tid] || (v2 == sv[tid] && i2 < si[tid])) { sv[tid] = v2; si[tid] = i2; }
            }
            __syncthreads();
        }
        if (tid == 0) { selIdx[k] = si[0]; selVal[k] = sv[0]; }
        __syncthreads();
    }
    if (tid == 0) {
        float s = 0.0f;
        for (int k = 0; k < TOPK; k++) s += selVal[k];
        int np = (int)s;            // trunc toward zero, s >= 0
        if (np < 1) np = 1;
        snum = np;
    }
    __syncthreads();
    if (tid < snum) R[selIdx[tid]] = selVal[tid] + 3.0f;
}

// ---------- K3: reg column pass -> overlap_t, conf class; count positives ----------
__global__ void k_col_reg(const float* __restrict__ F, const int* __restrict__ labels,
                          float* __restrict__ overlap, int* __restrict__ confcls,
                          unsigned int* __restrict__ posCount, int P) {
    int n = blockIdx.y;
    int p = blockIdx.x * blockDim.x + threadIdx.x;
    __shared__ int lab[16];
    if (threadIdx.x < 16) lab[threadIdx.x] = labels[n * 16 + threadIdx.x];
    __syncthreads();
    bool active = (p < P);
    float m = -1.0f; int best = 0;
    if (active) {
        const float* col = F + ((size_t)n * 16) * P + p;
        #pragma unroll
        for (int o = 0; o < 16; o++) {
            float v = col[(size_t)o * P];
            if (v > m) { m = v; best = o; }     // first argmax on ties
        }
        overlap[(size_t)n * P + p] = m;
        confcls[(size_t)n * P + p] = lab[best];
    }
    unsigned long long mask = __ballot(active && (m > 3.0f));
    if ((threadIdx.x & 63) == 0 && mask) atomicAdd(posCount, (unsigned int)__popcll(mask));
}

// ---------- K4: fused conf_data pass: pc gather + pred matrix + gfocal loss ----------
__global__ void k_conf(const float* __restrict__ conf, const float* __restrict__ priors,
                       const float* __restrict__ truths, const int* __restrict__ labels,
                       const float* __restrict__ overlap, const int* __restrict__ confcls,
                       float* __restrict__ F, double* __restrict__ accC,
                       int P, int C) {
    int n = blockIdx.y;
    int p = blockIdx.x * blockDim.x + threadIdx.x;
    __shared__ float strt[64];
    __shared__ int lab[16];
    if (threadIdx.x < 16) lab[threadIdx.x] = labels[n * 16 + threadIdx.x];
    if (threadIdx.x < 64) strt[threadIdx.x] = truths[n * 64 + threadIdx.x];
    __syncthreads();

    float lsum = 0.0f;
    if (p < P) {
        const float* row = conf + ((size_t)n * P + p) * (size_t)C;
        // ---- pred path: pc gather + ov^((2-pc)/2), column-max filter
        float4 pr = *(const float4*)(priors + (size_t)p * 4);
        float px1 = pr.x - pr.z * 0.5f, py1 = pr.y - pr.w * 0.5f;
        float px2 = pr.x + pr.z * 0.5f, py2 = pr.y + pr.w * 0.5f;
        float pv[16];
        float m = -1.0f;
        #pragma unroll
        for (int o = 0; o < 16; o++) {
            float lg = row[lab[o]];                      // L1/L2 hit mostly
            float pc = 1.0f / (1.0f + expf(-lg));
            float ov = iou_xyxy(strt[o * 4], strt[o * 4 + 1], strt[o * 4 + 2], strt[o * 4 + 3],
                                px1, py1, px2, py2);
            float e = (2.0f - pc) * 0.5f;
            float pd = powf(ov, e);                      // 0^e = 0
            pv[o] = pd;
            m = fmaxf(m, pd);
        }
        size_t base = ((size_t)n * 16) * P + p;
        #pragma unroll
        for (int o = 0; o < 16; o++) F[base + (size_t)o * P] = (pv[o] == m) ? pv[o] : 0.0f;

        // ---- gfocal over all C classes
        float ovl = overlap[(size_t)n * P + p];
        int   tc  = (ovl > 1.0f) ? confcls[(size_t)n * P + p] : -1;
        float vt  = fmaxf(ovl - 3.0f, 0.0f);
        for (int c = 0; c < C; c += 4) {
            float4 l4 = *(const float4*)(row + c);
            float lv[4] = {l4.x, l4.y, l4.z, l4.w};
            #pragma unroll
            for (int j = 0; j < 4; j++) {
                float t  = ((c + j) == tc) ? vt : 0.0f;
                float lg = lv[j];
                float bce = fmaxf(lg, 0.0f) - lg * t + log1pf(expf(-fabsf(lg)));
                float sg  = 1.0f / (1.0f + expf(-lg));
                float d   = sg - t;
                lsum += d * d * bce;
            }
        }
    }
    // block reduce (4 waves) -> f64 atomic
    double dv = (double)lsum;
    for (int s = 32; s > 0; s >>= 1) dv += __shfl_down(dv, s, 64);
    __shared__ double bsum[4];
    int wid = threadIdx.x >> 6;
    if ((threadIdx.x & 63) == 0) bsum[wid] = dv;
    __syncthreads();
    if (threadIdx.x == 0) {
        double tot = bsum[0] + bsum[1] + bsum[2] + bsum[3];
        atomicAdd(accC, tot);
    }
}

// ---------- K6: pred column pass -> pred_t + balanced-L1 accumulation ----------
__global__ void k_col_pred(const float* __restrict__ F, const float* __restrict__ loc,
                           const float* __restrict__ priors, const float* __restrict__ truths,
                           double* __restrict__ accL, double* __restrict__ accR, int P) {
    int n = blockIdx.y;
    int p = blockIdx.x * blockDim.x + threadIdx.x;
    __shared__ float strt[64];
    if (threadIdx.x < 64) strt[threadIdx.x] = truths[n * 64 + threadIdx.x];
    __syncthreads();

    float r = 0.0f, contrib = 0.0f;
    if (p < P) {
        const float* col = F + ((size_t)n * 16) * P + p;
        float m = -1.0f; int best = 0;
        #pragma unroll
        for (int o = 0; o < 16; o++) {
            float v = col[(size_t)o * P];
            if (v > m) { m = v; best = o; }
        }
        r = fmaxf(m - 3.0f, 0.0f);
        if (r > 0.0f) {
            const float Bc   = (float)19.085536923187668;  // e^(gamma/alpha) - 1
            const float beta = 0.11f;
            float4 pr = *(const float4*)(priors + (size_t)p * 4);
            float tx1 = strt[best * 4],     ty1 = strt[best * 4 + 1];
            float tx2 = strt[best * 4 + 2], ty2 = strt[best * 4 + 3];
            float gcx = ((tx1 + tx2) * 0.5f - pr.x) / (0.1f * pr.z);
            float gcy = ((ty1 + ty2) * 0.5f - pr.y) / (0.1f * pr.w);
            float gw  = logf((tx2 - tx1) / pr.z) / 0.2f;
            float gh  = logf((ty2 - ty1) / pr.w) / 0.2f;
            float4 l  = *(const float4*)(loc + ((size_t)n * P + p) * 4);
            float tgt[4] = {gcx, gcy, gw, gh};
            float lv[4]  = {l.x, l.y, l.z, l.w};
            float s = 0.0f;
            #pragma unroll
            for (int j = 0; j < 4; j++) {
                float diff = fabsf(lv[j] - tgt[j]);
                float bl;
                if (diff < beta) {
                    bl = 0.5f / Bc * (Bc * diff + 1.0f) * log1pf(Bc * diff / beta) - 0.5f * diff;
                } else {
                    bl = 1.5f * diff + 1.5f / Bc - 0.5f * beta;
                }
                s += bl;
            }
            contrib = r * s;
        }
    }
    double dl = (double)contrib, dr = (double)r;
    for (int s = 32; s > 0; s >>= 1) { dl += __shfl_down(dl, s, 64); dr += __shfl_down(dr, s, 64); }
    __shared__ double bl_[4], br_[4];
    int wid = threadIdx.x >> 6;
    if ((threadIdx.x & 63) == 0) { bl_[wid] = dl; br_[wid] = dr; }
    __syncthreads();
    if (threadIdx.x == 0) {
        double tl = bl_[0] + bl_[1] + bl_[2] + bl_[3];
        double tr2 = br_[0] + br_[1] + br_[2] + br_[3];
        atomicAdd(accL, tl);
        atomicAdd(accR, tr2);
    }
}

// ---------- K7: finalize ----------
__global__ void k_final(const double* accC, const double* accL, const double* accR,
                        const unsigned int* posCount, float* out) {
    if (threadIdx.x == 0) {
        unsigned int pc = *posCount;
        double npos = (double)(pc > 0u ? pc : 1u);
        double denom = 4.0 * (*accR);
        out[0] = (float)((*accL) / denom);   // loss_l
        out[1] = (float)((*accC) / npos);    // loss_c
    }
}

extern "C" void kernel_launch(void* const* d_in, const int* in_sizes, int n_in,
                              void* d_out, int out_size, void* d_ws, size_t ws_size,
                              hipStream_t stream) {
    const float* loc    = (const float*)d_in[0];
    const float* conf   = (const float*)d_in[1];
    const float* priors = (const float*)d_in[2];
    const float* truths = (const float*)d_in[3];
    const int*   labels = (const int*)d_in[4];

    int P = in_sizes[2] / 4;                 // 18000
    int N = in_sizes[0] / (P * 4);           // 32
    int C = in_sizes[1] / (N * P);           // 80
    // O assumed 16 (hard-coded in kernels), TOPK = 15

    char* ws = (char*)d_ws;
    double* accC = (double*)ws;
    double* accL = accC + 1;
    double* accR = accC + 2;
    unsigned int* posCount = (unsigned int*)(accC + 3);
    float* F       = (float*)(ws + 64);                  // N*16*P floats (36.9 MB), reused
    float* overlap = F + (size_t)N * 16 * P;             // N*P floats
    int*   confcls = (int*)(overlap + (size_t)N * P);    // N*P ints
    float* out = (float*)d_out;

    dim3 blk(256);
    dim3 gridP((P + 255) / 256, N);

    k_zero<<<1, 64, 0, stream>>>(accC, accL, accR, posCount);
    k_reg_matrix<<<gridP, blk, 0, stream>>>(loc, priors, truths, F, P);
    k_topk_boost<<<N * 16, blk, 0, stream>>>(F, P);
    k_col_reg<<<gridP, blk, 0, stream>>>(F, labels, overlap, confcls, posCount, P);
    k_conf<<<gridP, blk, 0, stream>>>(conf, priors, truths, labels, overlap, confcls,
                                      F, accC, P, C);
    k_topk_boost<<<N * 16, blk, 0, stream>>>(F, P);
    k_col_pred<<<gridP, blk, 0, stream>>>(F, loc, priors, truths, accL, accR, P);
    k_final<<<1, 1, 0, stream>>>(accC, accL, accR, posCount, out);
}

// Round 2
// 471.635 us; speedup vs baseline: 4.1416x; 4.1416x over previous
//
#include <hip/hip_runtime.h>
#include <hip/hip_bf16.h>

#define TOPK 15

// ---------- helpers ----------
__device__ __forceinline__ float iou_xyxy(float ax1, float ay1, float ax2, float ay2,
                                          float bx1, float by1, float bx2, float by2) {
    float ltx = fmaxf(ax1, bx1), lty = fmaxf(ay1, by1);
    float rbx = fminf(ax2, bx2), rby = fminf(ay2, by2);
    float w = fmaxf(rbx - ltx, 0.0f), h = fmaxf(rby - lty, 0.0f);
    float inter = w * h;
    float areaA = (ax2 - ax1) * (ay2 - ay1);
    float areaB = (bx2 - bx1) * (by2 - by1);
    return inter / (areaA + areaB - inter);
}

// ---------- K0: zero accumulators ----------
__global__ void k_zero(double* accC, double* accL, double* accR, unsigned int* posCount) {
    if (threadIdx.x == 0) {
        *accC = 0.0; *accL = 0.0; *accR = 0.0; *posCount = 0u;
    }
}

// ---------- K1: reg matrix  F[n][o][p] = filtered jaccard(truths, decode(loc)) ----------
__global__ void k_reg_matrix(const float* __restrict__ loc, const float* __restrict__ priors,
                             const float* __restrict__ truths, float* __restrict__ F,
                             int P) {
    int n = blockIdx.y;
    int p = blockIdx.x * blockDim.x + threadIdx.x;
    __shared__ float tr[64];
    if (threadIdx.x < 64) tr[threadIdx.x] = truths[n * 64 + threadIdx.x];
    __syncthreads();
    if (p >= P) return;
    float4 pr = *(const float4*)(priors + (size_t)p * 4);
    float4 l  = *(const float4*)(loc + ((size_t)n * P + p) * 4);
    float cx = pr.x + l.x * 0.1f * pr.z;
    float cy = pr.y + l.y * 0.1f * pr.w;
    float w  = pr.z * expf(l.z * 0.2f);
    float h  = pr.w * expf(l.w * 0.2f);
    float bx1 = cx - w * 0.5f, by1 = cy - h * 0.5f;
    float bx2 = cx + w * 0.5f, by2 = cy + h * 0.5f;
    float v[16];
    float m = -1.0f;
    #pragma unroll
    for (int o = 0; o < 16; o++) {
        v[o] = iou_xyxy(tr[o * 4], tr[o * 4 + 1], tr[o * 4 + 2], tr[o * 4 + 3],
                        bx1, by1, bx2, by2);
        m = fmaxf(m, v[o]);
    }
    size_t base = ((size_t)n * 16) * P + p;
    #pragma unroll
    for (int o = 0; o < 16; o++) {
        F[base + (size_t)o * P] = (v[o] == m) ? v[o] : 0.0f;
    }
}

// ---------- K2/K5: single-pass per-row top-15 + boost (exact jax.lax.top_k tie-break) ----
// One block per row. Each thread keeps a sorted top-15 of its strided slice in
// registers (static indexing only), then a 15-round merge of list heads via
// packed u64 keys: (float_bits(v) << 32) | ~idx  -> value desc, index asc.
__global__ __launch_bounds__(256) void k_topk_boost(float* __restrict__ F, int P) {
    int row = blockIdx.x;
    float* R = F + (size_t)row * P;
    int tid = threadIdx.x;

    float lv[TOPK];
    int   li[TOPK];
    #pragma unroll
    for (int k = 0; k < TOPK; k++) { lv[k] = -1.0f; li[k] = 0x7FFFFFFF; }

    // vectorized single scan
    int nf4 = P >> 2;
    const float4* R4 = (const float4*)R;
    for (int f = tid; f < nf4; f += 256) {
        float4 q = R4[f];
        float vals[4] = {q.x, q.y, q.z, q.w};
        #pragma unroll
        for (int j = 0; j < 4; j++) {
            float v = vals[j];
            if (v > lv[TOPK - 1]) {
                int i = 4 * f + j;
                #pragma unroll
                for (int k = TOPK - 1; k >= 0; k--) {
                    bool shift = (k > 0) && (v > lv[k - 1]);
                    if (shift)            { lv[k] = lv[k - 1]; li[k] = li[k - 1]; }
                    else if (v > lv[k])   { lv[k] = v;         li[k] = i; }
                }
            }
        }
    }
    for (int i = (nf4 << 2) + tid; i < P; i += 256) {
        float v = R[i];
        if (v > lv[TOPK - 1]) {
            #pragma unroll
            for (int k = TOPK - 1; k >= 0; k--) {
                bool shift = (k > 0) && (v > lv[k - 1]);
                if (shift)          { lv[k] = lv[k - 1]; li[k] = li[k - 1]; }
                else if (v > lv[k]) { lv[k] = v;         li[k] = i; }
            }
        }
    }

    // dump sorted lists to LDS as packed keys (0 == empty sentinel)
    __shared__ unsigned long long cand[256 * TOPK];   // 30 KB
    #pragma unroll
    for (int k = 0; k < TOPK; k++) {
        unsigned long long key = 0ULL;
        if (lv[k] >= 0.0f) {
            unsigned int fb = __float_as_uint(lv[k]);
            key = ((unsigned long long)fb << 32) | (unsigned int)(~(unsigned int)li[k]);
        }
        cand[tid * TOPK + k] = key;
    }
    __syncthreads();

    __shared__ unsigned long long wmax[4];
    __shared__ unsigned long long selKey[TOPK];
    __shared__ int s_num;

    int hp = 0;
    for (int k = 0; k < TOPK; k++) {
        unsigned long long prop = (hp < TOPK) ? cand[tid * TOPK + hp] : 0ULL;
        unsigned long long m = prop;
        #pragma unroll
        for (int s = 32; s > 0; s >>= 1) {
            unsigned long long o = __shfl_down(m, s, 64);
            if (o > m) m = o;
        }
        if ((tid & 63) == 0) wmax[tid >> 6] = m;
        __syncthreads();
        if (tid == 0) {
            unsigned long long w = wmax[0];
            if (wmax[1] > w) w = wmax[1];
            if (wmax[2] > w) w = wmax[2];
            if (wmax[3] > w) w = wmax[3];
            selKey[k] = w;
        }
        __syncthreads();
        unsigned long long w = selKey[k];
        if (w != 0ULL && prop == w) hp++;
    }

    if (tid == 0) {
        float s = 0.0f;
        #pragma unroll
        for (int k = 0; k < TOPK; k++)
            s += __uint_as_float((unsigned int)(selKey[k] >> 32));
        int np = (int)s;                 // trunc, s >= 0
        if (np < 1) np = 1;
        s_num = np;
    }
    __syncthreads();
    if (tid < TOPK && tid < s_num) {
        unsigned long long w = selKey[tid];
        if (w != 0ULL) {
            int idx = (int)(~(unsigned int)(w & 0xFFFFFFFFull));
            float v = __uint_as_float((unsigned int)(w >> 32));
            R[idx] = v + 3.0f;
        }
    }
}

// ---------- K3: reg column pass -> overlap_t, conf class; count positives ----------
__global__ void k_col_reg(const float* __restrict__ F, const int* __restrict__ labels,
                          float* __restrict__ overlap, int* __restrict__ confcls,
                          unsigned int* __restrict__ posCount, int P) {
    int n = blockIdx.y;
    int p = blockIdx.x * blockDim.x + threadIdx.x;
    __shared__ int lab[16];
    if (threadIdx.x < 16) lab[threadIdx.x] = labels[n * 16 + threadIdx.x];
    __syncthreads();
    bool active = (p < P);
    float m = -1.0f; int best = 0;
    if (active) {
        const float* col = F + ((size_t)n * 16) * P + p;
        #pragma unroll
        for (int o = 0; o < 16; o++) {
            float v = col[(size_t)o * P];
            if (v > m) { m = v; best = o; }
        }
        overlap[(size_t)n * P + p] = m;
        confcls[(size_t)n * P + p] = lab[best];
    }
    unsigned long long mask = __ballot(active && (m > 3.0f));
    if ((threadIdx.x & 63) == 0 && mask) atomicAdd(posCount, (unsigned int)__popcll(mask));
}

// ---------- K4: fused conf_data pass: pc gather + pred matrix + gfocal loss ----------
__global__ void k_conf(const float* __restrict__ conf, const float* __restrict__ priors,
                       const float* __restrict__ truths, const int* __restrict__ labels,
                       const float* __restrict__ overlap, const int* __restrict__ confcls,
                       float* __restrict__ F, double* __restrict__ accC,
                       int P, int C) {
    int n = blockIdx.y;
    int p = blockIdx.x * blockDim.x + threadIdx.x;
    __shared__ float strt[64];
    __shared__ int lab[16];
    if (threadIdx.x < 16) lab[threadIdx.x] = labels[n * 16 + threadIdx.x];
    if (threadIdx.x < 64) strt[threadIdx.x] = truths[n * 64 + threadIdx.x];
    __syncthreads();

    float lsum = 0.0f;
    if (p < P) {
        const float* row = conf + ((size_t)n * P + p) * (size_t)C;
        float4 pr = *(const float4*)(priors + (size_t)p * 4);
        float px1 = pr.x - pr.z * 0.5f, py1 = pr.y - pr.w * 0.5f;
        float px2 = pr.x + pr.z * 0.5f, py2 = pr.y + pr.w * 0.5f;
        float pv[16];
        float m = -1.0f;
        #pragma unroll
        for (int o = 0; o < 16; o++) {
            float lg = row[lab[o]];
            float pc = 1.0f / (1.0f + expf(-lg));
            float ov = iou_xyxy(strt[o * 4], strt[o * 4 + 1], strt[o * 4 + 2], strt[o * 4 + 3],
                                px1, py1, px2, py2);
            float e = (2.0f - pc) * 0.5f;
            float pd = powf(ov, e);
            pv[o] = pd;
            m = fmaxf(m, pd);
        }
        size_t base = ((size_t)n * 16) * P + p;
        #pragma unroll
        for (int o = 0; o < 16; o++) F[base + (size_t)o * P] = (pv[o] == m) ? pv[o] : 0.0f;

        float ovl = overlap[(size_t)n * P + p];
        int   tc  = (ovl > 1.0f) ? confcls[(size_t)n * P + p] : -1;
        float vt  = fmaxf(ovl - 3.0f, 0.0f);
        for (int c = 0; c < C; c += 4) {
            float4 l4 = *(const float4*)(row + c);
            float lvv[4] = {l4.x, l4.y, l4.z, l4.w};
            #pragma unroll
            for (int j = 0; j < 4; j++) {
                float t  = ((c + j) == tc) ? vt : 0.0f;
                float lg = lvv[j];
                float bce = fmaxf(lg, 0.0f) - lg * t + log1pf(expf(-fabsf(lg)));
                float sg  = 1.0f / (1.0f + expf(-lg));
                float d   = sg - t;
                lsum += d * d * bce;
            }
        }
    }
    double dv = (double)lsum;
    for (int s = 32; s > 0; s >>= 1) dv += __shfl_down(dv, s, 64);
    __shared__ double bsum[4];
    int wid = threadIdx.x >> 6;
    if ((threadIdx.x & 63) == 0) bsum[wid] = dv;
    __syncthreads();
    if (threadIdx.x == 0) {
        double tot = bsum[0] + bsum[1] + bsum[2] + bsum[3];
        atomicAdd(accC, tot);
    }
}

// ---------- K6: pred column pass -> pred_t + balanced-L1 accumulation ----------
__global__ void k_col_pred(const float* __restrict__ F, const float* __restrict__ loc,
                           const float* __restrict__ priors, const float* __restrict__ truths,
                           double* __restrict__ accL, double* __restrict__ accR, int P) {
    int n = blockIdx.y;
    int p = blockIdx.x * blockDim.x + threadIdx.x;
    __shared__ float strt[64];
    if (threadIdx.x < 64) strt[threadIdx.x] = truths[n * 64 + threadIdx.x];
    __syncthreads();

    float r = 0.0f, contrib = 0.0f;
    if (p < P) {
        const float* col = F + ((size_t)n * 16) * P + p;
        float m = -1.0f; int best = 0;
        #pragma unroll
        for (int o = 0; o < 16; o++) {
            float v = col[(size_t)o * P];
            if (v > m) { m = v; best = o; }
        }
        r = fmaxf(m - 3.0f, 0.0f);
        if (r > 0.0f) {
            const float Bc   = (float)19.085536923187668;
            const float beta = 0.11f;
            float4 pr = *(const float4*)(priors + (size_t)p * 4);
            float tx1 = strt[best * 4],     ty1 = strt[best * 4 + 1];
            float tx2 = strt[best * 4 + 2], ty2 = strt[best * 4 + 3];
            float gcx = ((tx1 + tx2) * 0.5f - pr.x) / (0.1f * pr.z);
            float gcy = ((ty1 + ty2) * 0.5f - pr.y) / (0.1f * pr.w);
            float gw  = logf((tx2 - tx1) / pr.z) / 0.2f;
            float gh  = logf((ty2 - ty1) / pr.w) / 0.2f;
            float4 l  = *(const float4*)(loc + ((size_t)n * P + p) * 4);
            float tgt[4] = {gcx, gcy, gw, gh};
            float lvv[4] = {l.x, l.y, l.z, l.w};
            float s = 0.0f;
            #pragma unroll
            for (int j = 0; j < 4; j++) {
                float diff = fabsf(lvv[j] - tgt[j]);
                float bl;
                if (diff < beta) {
                    bl = 0.5f / Bc * (Bc * diff + 1.0f) * log1pf(Bc * diff / beta) - 0.5f * diff;
                } else {
                    bl = 1.5f * diff + 1.5f / Bc - 0.5f * beta;
                }
                s += bl;
            }
            contrib = r * s;
        }
    }
    double dl = (double)contrib, dr = (double)r;
    for (int s = 32; s > 0; s >>= 1) { dl += __shfl_down(dl, s, 64); dr += __shfl_down(dr, s, 64); }
    __shared__ double bl_[4], br_[4];
    int wid = threadIdx.x >> 6;
    if ((threadIdx.x & 63) == 0) { bl_[wid] = dl; br_[wid] = dr; }
    __syncthreads();
    if (threadIdx.x == 0) {
        double tl  = bl_[0] + bl_[1] + bl_[2] + bl_[3];
        double tr2 = br_[0] + br_[1] + br_[2] + br_[3];
        atomicAdd(accL, tl);
        atomicAdd(accR, tr2);
    }
}

// ---------- K7: finalize ----------
__global__ void k_final(const double* accC, const double* accL, const double* accR,
                        const unsigned int* posCount, float* out) {
    if (threadIdx.x == 0) {
        unsigned int pc = *posCount;
        double npos = (double)(pc > 0u ? pc : 1u);
        double denom = 4.0 * (*accR);
        out[0] = (float)((*accL) / denom);
        out[1] = (float)((*accC) / npos);
    }
}

extern "C" void kernel_launch(void* const* d_in, const int* in_sizes, int n_in,
                              void* d_out, int out_size, void* d_ws, size_t ws_size,
                              hipStream_t stream) {
    const float* loc    = (const float*)d_in[0];
    const float* conf   = (const float*)d_in[1];
    const float* priors = (const float*)d_in[2];
    const float* truths = (const float*)d_in[3];
    const int*   labels = (const int*)d_in[4];

    int P = in_sizes[2] / 4;                 // 18000
    int N = in_sizes[0] / (P * 4);           // 32
    int C = in_sizes[1] / (N * P);           // 80

    char* ws = (char*)d_ws;
    double* accC = (double*)ws;
    double* accL = accC + 1;
    double* accR = accC + 2;
    unsigned int* posCount = (unsigned int*)(accC + 3);
    float* F       = (float*)(ws + 64);
    float* overlap = F + (size_t)N * 16 * P;
    int*   confcls = (int*)(overlap + (size_t)N * P);
    float* out = (float*)d_out;

    dim3 blk(256);
    dim3 gridP((P + 255) / 256, N);

    k_zero<<<1, 64, 0, stream>>>(accC, accL, accR, posCount);
    k_reg_matrix<<<gridP, blk, 0, stream>>>(loc, priors, truths, F, P);
    k_topk_boost<<<N * 16, blk, 0, stream>>>(F, P);
    k_col_reg<<<gridP, blk, 0, stream>>>(F, labels, overlap, confcls, posCount, P);
    k_conf<<<gridP, blk, 0, stream>>>(conf, priors, truths, labels, overlap, confcls,
                                      F, accC, P, C);
    k_topk_boost<<<N * 16, blk, 0, stream>>>(F, P);
    k_col_pred<<<gridP, blk, 0, stream>>>(F, loc, priors, truths, accL, accR, P);
    k_final<<<1, 1, 0, stream>>>(accC, accL, accR, posCount, out);
}

// Round 3
// 417.876 us; speedup vs baseline: 4.6744x; 1.1286x over previous
//
#include <hip/hip_runtime.h>
#include <hip/hip_bf16.h>

#define TOPK 15
#define LOG2E 1.44269504088896340736f
#define LN2   0.69314718055994530942f

// ---------- fast math ----------
__device__ __forceinline__ float fexp2(float x) { return __builtin_amdgcn_exp2f(x); }
__device__ __forceinline__ float flog2(float x) { return __builtin_amdgcn_logf(x); }
__device__ __forceinline__ float frcp(float x)  { return __builtin_amdgcn_rcpf(x); }
__device__ __forceinline__ float fsigmoid(float x) {
    float e = fexp2(-fabsf(x) * LOG2E);
    float r = frcp(1.0f + e);
    return x >= 0.0f ? r : e * r;
}

// ---------- helpers ----------
__device__ __forceinline__ float iou_xyxy(float ax1, float ay1, float ax2, float ay2,
                                          float bx1, float by1, float bx2, float by2) {
    float ltx = fmaxf(ax1, bx1), lty = fmaxf(ay1, by1);
    float rbx = fminf(ax2, bx2), rby = fminf(ay2, by2);
    float w = fmaxf(rbx - ltx, 0.0f), h = fmaxf(rby - lty, 0.0f);
    float inter = w * h;
    float areaA = (ax2 - ax1) * (ay2 - ay1);
    float areaB = (bx2 - bx1) * (by2 - by1);
    return inter / (areaA + areaB - inter);
}

// ---------- K0: zero accumulators ----------
__global__ void k_zero(double* accC, double* accL, double* accR, unsigned int* posCount) {
    if (threadIdx.x == 0) {
        *accC = 0.0; *accL = 0.0; *accR = 0.0; *posCount = 0u;
    }
}

// ---------- K1: reg matrix ----------
__global__ void k_reg_matrix(const float* __restrict__ loc, const float* __restrict__ priors,
                             const float* __restrict__ truths, float* __restrict__ F,
                             int P) {
    int n = blockIdx.y;
    int p = blockIdx.x * blockDim.x + threadIdx.x;
    __shared__ float tr[64];
    if (threadIdx.x < 64) tr[threadIdx.x] = truths[n * 64 + threadIdx.x];
    __syncthreads();
    if (p >= P) return;
    float4 pr = *(const float4*)(priors + (size_t)p * 4);
    float4 l  = *(const float4*)(loc + ((size_t)n * P + p) * 4);
    float cx = pr.x + l.x * 0.1f * pr.z;
    float cy = pr.y + l.y * 0.1f * pr.w;
    float w  = pr.z * fexp2(l.z * 0.2f * LOG2E);
    float h  = pr.w * fexp2(l.w * 0.2f * LOG2E);
    float bx1 = cx - w * 0.5f, by1 = cy - h * 0.5f;
    float bx2 = cx + w * 0.5f, by2 = cy + h * 0.5f;
    float v[16];
    float m = -1.0f;
    #pragma unroll
    for (int o = 0; o < 16; o++) {
        v[o] = iou_xyxy(tr[o * 4], tr[o * 4 + 1], tr[o * 4 + 2], tr[o * 4 + 3],
                        bx1, by1, bx2, by2);
        m = fmaxf(m, v[o]);
    }
    size_t base = ((size_t)n * 16) * P + p;
    #pragma unroll
    for (int o = 0; o < 16; o++) {
        F[base + (size_t)o * P] = (v[o] == m) ? v[o] : 0.0f;
    }
}

// ---------- K2/K5: single-pass per-row top-15 + boost ----------
__global__ __launch_bounds__(256) void k_topk_boost(float* __restrict__ F, int P) {
    int row = blockIdx.x;
    float* R = F + (size_t)row * P;
    int tid = threadIdx.x;

    float lv[TOPK];
    int   li[TOPK];
    #pragma unroll
    for (int k = 0; k < TOPK; k++) { lv[k] = -1.0f; li[k] = 0x7FFFFFFF; }

    int nf4 = P >> 2;
    const float4* R4 = (const float4*)R;
    for (int f = tid; f < nf4; f += 256) {
        float4 q = R4[f];
        float vals[4] = {q.x, q.y, q.z, q.w};
        #pragma unroll
        for (int j = 0; j < 4; j++) {
            float v = vals[j];
            if (v > lv[TOPK - 1]) {
                int i = 4 * f + j;
                #pragma unroll
                for (int k = TOPK - 1; k >= 0; k--) {
                    bool shift = (k > 0) && (v > lv[k - 1]);
                    if (shift)            { lv[k] = lv[k - 1]; li[k] = li[k - 1]; }
                    else if (v > lv[k])   { lv[k] = v;         li[k] = i; }
                }
            }
        }
    }
    for (int i = (nf4 << 2) + tid; i < P; i += 256) {
        float v = R[i];
        if (v > lv[TOPK - 1]) {
            #pragma unroll
            for (int k = TOPK - 1; k >= 0; k--) {
                bool shift = (k > 0) && (v > lv[k - 1]);
                if (shift)          { lv[k] = lv[k - 1]; li[k] = li[k - 1]; }
                else if (v > lv[k]) { lv[k] = v;         li[k] = i; }
            }
        }
    }

    __shared__ unsigned long long cand[256 * TOPK];   // 30 KB
    #pragma unroll
    for (int k = 0; k < TOPK; k++) {
        unsigned long long key = 0ULL;
        if (lv[k] >= 0.0f) {
            unsigned int fb = __float_as_uint(lv[k]);
            key = ((unsigned long long)fb << 32) | (unsigned int)(~(unsigned int)li[k]);
        }
        cand[tid * TOPK + k] = key;
    }
    __syncthreads();

    __shared__ unsigned long long wmax[4];
    __shared__ unsigned long long selKey[TOPK];
    __shared__ int s_num;

    int hp = 0;
    for (int k = 0; k < TOPK; k++) {
        unsigned long long prop = (hp < TOPK) ? cand[tid * TOPK + hp] : 0ULL;
        unsigned long long m = prop;
        #pragma unroll
        for (int s = 32; s > 0; s >>= 1) {
            unsigned long long o = __shfl_down(m, s, 64);
            if (o > m) m = o;
        }
        if ((tid & 63) == 0) wmax[tid >> 6] = m;
        __syncthreads();
        if (tid == 0) {
            unsigned long long w = wmax[0];
            if (wmax[1] > w) w = wmax[1];
            if (wmax[2] > w) w = wmax[2];
            if (wmax[3] > w) w = wmax[3];
            selKey[k] = w;
        }
        __syncthreads();
        unsigned long long w = selKey[k];
        if (w != 0ULL && prop == w) hp++;
    }

    if (tid == 0) {
        float s = 0.0f;
        #pragma unroll
        for (int k = 0; k < TOPK; k++)
            s += __uint_as_float((unsigned int)(selKey[k] >> 32));
        int np = (int)s;
        if (np < 1) np = 1;
        s_num = np;
    }
    __syncthreads();
    if (tid < TOPK && tid < s_num) {
        unsigned long long w = selKey[tid];
        if (w != 0ULL) {
            int idx = (int)(~(unsigned int)(w & 0xFFFFFFFFull));
            float v = __uint_as_float((unsigned int)(w >> 32));
            R[idx] = v + 3.0f;
        }
    }
}

// ---------- K3: reg column pass ----------
__global__ void k_col_reg(const float* __restrict__ F, const int* __restrict__ labels,
                          float* __restrict__ overlap, int* __restrict__ confcls,
                          unsigned int* __restrict__ posCount, int P) {
    int n = blockIdx.y;
    int p = blockIdx.x * blockDim.x + threadIdx.x;
    __shared__ int lab[16];
    if (threadIdx.x < 16) lab[threadIdx.x] = labels[n * 16 + threadIdx.x];
    __syncthreads();
    bool active = (p < P);
    float m = -1.0f; int best = 0;
    if (active) {
        const float* col = F + ((size_t)n * 16) * P + p;
        #pragma unroll
        for (int o = 0; o < 16; o++) {
            float v = col[(size_t)o * P];
            if (v > m) { m = v; best = o; }
        }
        overlap[(size_t)n * P + p] = m;
        confcls[(size_t)n * P + p] = lab[best];
    }
    unsigned long long mask = __ballot(active && (m > 3.0f));
    if ((threadIdx.x & 63) == 0 && mask) atomicAdd(posCount, (unsigned int)__popcll(mask));
}

// ---------- K4: fused conf_data pass (gfocal first -> gather second, fast math) ------
__global__ void k_conf(const float* __restrict__ conf, const float* __restrict__ priors,
                       const float* __restrict__ truths, const int* __restrict__ labels,
                       const float* __restrict__ overlap, const int* __restrict__ confcls,
                       float* __restrict__ F, double* __restrict__ accC,
                       int P, int C) {
    int n = blockIdx.y;
    int p = blockIdx.x * blockDim.x + threadIdx.x;
    __shared__ float strt[64];
    __shared__ int lab[16];
    if (threadIdx.x < 16) lab[threadIdx.x] = labels[n * 16 + threadIdx.x];
    if (threadIdx.x < 64) strt[threadIdx.x] = truths[n * 64 + threadIdx.x];
    __syncthreads();

    float lsum = 0.0f;
    if (p < P) {
        const float* row = conf + ((size_t)n * P + p) * (size_t)C;

        // ---- gfocal over all C classes (streams the row once)
        float ovl = overlap[(size_t)n * P + p];
        int   tc  = (ovl > 1.0f) ? confcls[(size_t)n * P + p] : -1;
        float vt  = fmaxf(ovl - 3.0f, 0.0f);
        for (int c = 0; c < C; c += 4) {
            float4 l4 = *(const float4*)(row + c);
            float lvv[4] = {l4.x, l4.y, l4.z, l4.w};
            #pragma unroll
            for (int j = 0; j < 4; j++) {
                float lg = lvv[j];
                float t  = ((c + j) == tc) ? vt : 0.0f;
                float e  = fexp2(-fabsf(lg) * LOG2E);
                float ln1pe = flog2(1.0f + e) * LN2;
                float r  = frcp(1.0f + e);
                float sg = (lg >= 0.0f) ? r : e * r;
                float bce = fmaxf(lg, 0.0f) - lg * t + ln1pe;
                float d  = sg - t;
                lsum += d * d * bce;
            }
        }

        // ---- pred path: label gather (row lines hot in L1/L2), ov^((2-pc)/2)
        float4 pr = *(const float4*)(priors + (size_t)p * 4);
        float px1 = pr.x - pr.z * 0.5f, py1 = pr.y - pr.w * 0.5f;
        float px2 = pr.x + pr.z * 0.5f, py2 = pr.y + pr.w * 0.5f;
        float pv[16];
        float m = -1.0f;
        #pragma unroll
        for (int o = 0; o < 16; o++) {
            float ov = iou_xyxy(strt[o * 4], strt[o * 4 + 1], strt[o * 4 + 2], strt[o * 4 + 3],
                                px1, py1, px2, py2);
            float pd = 0.0f;
            if (ov > 0.0f) {
                float pc = fsigmoid(row[lab[o]]);
                pd = fexp2((2.0f - pc) * 0.5f * flog2(ov));
            }
            pv[o] = pd;
            m = fmaxf(m, pd);
        }
        size_t base = ((size_t)n * 16) * P + p;
        #pragma unroll
        for (int o = 0; o < 16; o++) F[base + (size_t)o * P] = (pv[o] == m) ? pv[o] : 0.0f;
    }
    double dv = (double)lsum;
    for (int s = 32; s > 0; s >>= 1) dv += __shfl_down(dv, s, 64);
    __shared__ double bsum[4];
    int wid = threadIdx.x >> 6;
    if ((threadIdx.x & 63) == 0) bsum[wid] = dv;
    __syncthreads();
    if (threadIdx.x == 0) {
        double tot = bsum[0] + bsum[1] + bsum[2] + bsum[3];
        atomicAdd(accC, tot);
    }
}

// ---------- K6: pred column pass ----------
__global__ void k_col_pred(const float* __restrict__ F, const float* __restrict__ loc,
                           const float* __restrict__ priors, const float* __restrict__ truths,
                           double* __restrict__ accL, double* __restrict__ accR, int P) {
    int n = blockIdx.y;
    int p = blockIdx.x * blockDim.x + threadIdx.x;
    __shared__ float strt[64];
    if (threadIdx.x < 64) strt[threadIdx.x] = truths[n * 64 + threadIdx.x];
    __syncthreads();

    float r = 0.0f, contrib = 0.0f;
    if (p < P) {
        const float* col = F + ((size_t)n * 16) * P + p;
        float m = -1.0f; int best = 0;
        #pragma unroll
        for (int o = 0; o < 16; o++) {
            float v = col[(size_t)o * P];
            if (v > m) { m = v; best = o; }
        }
        r = fmaxf(m - 3.0f, 0.0f);
        if (r > 0.0f) {
            const float Bc   = (float)19.085536923187668;
            const float beta = 0.11f;
            float4 pr = *(const float4*)(priors + (size_t)p * 4);
            float tx1 = strt[best * 4],     ty1 = strt[best * 4 + 1];
            float tx2 = strt[best * 4 + 2], ty2 = strt[best * 4 + 3];
            float gcx = ((tx1 + tx2) * 0.5f - pr.x) / (0.1f * pr.z);
            float gcy = ((ty1 + ty2) * 0.5f - pr.y) / (0.1f * pr.w);
            float gw  = flog2((tx2 - tx1) / pr.z) * LN2 / 0.2f;
            float gh  = flog2((ty2 - ty1) / pr.w) * LN2 / 0.2f;
            float4 l  = *(const float4*)(loc + ((size_t)n * P + p) * 4);
            float tgt[4] = {gcx, gcy, gw, gh};
            float lvv[4] = {l.x, l.y, l.z, l.w};
            float s = 0.0f;
            #pragma unroll
            for (int j = 0; j < 4; j++) {
                float diff = fabsf(lvv[j] - tgt[j]);
                float bl;
                if (diff < beta) {
                    bl = 0.5f / Bc * (Bc * diff + 1.0f) * (flog2(1.0f + Bc * diff / beta) * LN2)
                         - 0.5f * diff;
                } else {
                    bl = 1.5f * diff + 1.5f / Bc - 0.5f * beta;
                }
                s += bl;
            }
            contrib = r * s;
        }
    }
    double dl = (double)contrib, dr = (double)r;
    for (int s = 32; s > 0; s >>= 1) { dl += __shfl_down(dl, s, 64); dr += __shfl_down(dr, s, 64); }
    __shared__ double bl_[4], br_[4];
    int wid = threadIdx.x >> 6;
    if ((threadIdx.x & 63) == 0) { bl_[wid] = dl; br_[wid] = dr; }
    __syncthreads();
    if (threadIdx.x == 0) {
        double tl  = bl_[0] + bl_[1] + bl_[2] + bl_[3];
        double tr2 = br_[0] + br_[1] + br_[2] + br_[3];
        atomicAdd(accL, tl);
        atomicAdd(accR, tr2);
    }
}

// ---------- K7: finalize ----------
__global__ void k_final(const double* accC, const double* accL, const double* accR,
                        const unsigned int* posCount, float* out) {
    if (threadIdx.x == 0) {
        unsigned int pc = *posCount;
        double npos = (double)(pc > 0u ? pc : 1u);
        double denom = 4.0 * (*accR);
        out[0] = (float)((*accL) / denom);
        out[1] = (float)((*accC) / npos);
    }
}

extern "C" void kernel_launch(void* const* d_in, const int* in_sizes, int n_in,
                              void* d_out, int out_size, void* d_ws, size_t ws_size,
                              hipStream_t stream) {
    const float* loc    = (const float*)d_in[0];
    const float* conf   = (const float*)d_in[1];
    const float* priors = (const float*)d_in[2];
    const float* truths = (const float*)d_in[3];
    const int*   labels = (const int*)d_in[4];

    int P = in_sizes[2] / 4;                 // 18000
    int N = in_sizes[0] / (P * 4);           // 32
    int C = in_sizes[1] / (N * P);           // 80

    char* ws = (char*)d_ws;
    double* accC = (double*)ws;
    double* accL = accC + 1;
    double* accR = accC + 2;
    unsigned int* posCount = (unsigned int*)(accC + 3);
    float* F       = (float*)(ws + 64);
    float* overlap = F + (size_t)N * 16 * P;
    int*   confcls = (int*)(overlap + (size_t)N * P);
    float* out = (float*)d_out;

    dim3 blk(256);
    dim3 gridP((P + 255) / 256, N);

    k_zero<<<1, 64, 0, stream>>>(accC, accL, accR, posCount);
    k_reg_matrix<<<gridP, blk, 0, stream>>>(loc, priors, truths, F, P);
    k_topk_boost<<<N * 16, blk, 0, stream>>>(F, P);
    k_col_reg<<<gridP, blk, 0, stream>>>(F, labels, overlap, confcls, posCount, P);
    k_conf<<<gridP, blk, 0, stream>>>(conf, priors, truths, labels, overlap, confcls,
                                      F, accC, P, C);
    k_topk_boost<<<N * 16, blk, 0, stream>>>(F, P);
    k_col_pred<<<gridP, blk, 0, stream>>>(F, loc, priors, truths, accL, accR, P);
    k_final<<<1, 1, 0, stream>>>(accC, accL, accR, posCount, out);
}

// Round 4
// 352.814 us; speedup vs baseline: 5.5365x; 1.1844x over previous
//
#include <hip/hip_runtime.h>
#include <hip/hip_bf16.h>

#define TOPK 15
#define LOG2E 1.44269504088896340736f
#define LN2   0.69314718055994530942f

// ---------- fast math ----------
__device__ __forceinline__ float fexp2(float x) { return __builtin_amdgcn_exp2f(x); }
__device__ __forceinline__ float flog2(float x) { return __builtin_amdgcn_logf(x); }
__device__ __forceinline__ float frcp(float x)  { return __builtin_amdgcn_rcpf(x); }
__device__ __forceinline__ float fsigmoid(float x) {
    float e = fexp2(-fabsf(x) * LOG2E);
    float r = frcp(1.0f + e);
    return x >= 0.0f ? r : e * r;
}

// ---------- helpers ----------
__device__ __forceinline__ float iou_xyxy(float ax1, float ay1, float ax2, float ay2,
                                          float bx1, float by1, float bx2, float by2) {
    float ltx = fmaxf(ax1, bx1), lty = fmaxf(ay1, by1);
    float rbx = fminf(ax2, bx2), rby = fminf(ay2, by2);
    float w = fmaxf(rbx - ltx, 0.0f), h = fmaxf(rby - lty, 0.0f);
    float inter = w * h;
    float areaA = (ax2 - ax1) * (ay2 - ay1);
    float areaB = (bx2 - bx1) * (by2 - by1);
    return inter / (areaA + areaB - inter);
}

// ---------- K0 ----------
__global__ void k_zero(double* accC, double* accL, double* accR, unsigned int* posCount) {
    if (threadIdx.x == 0) {
        *accC = 0.0; *accL = 0.0; *accR = 0.0; *posCount = 0u;
    }
}

// ---------- K1: reg matrix ----------
__global__ void k_reg_matrix(const float* __restrict__ loc, const float* __restrict__ priors,
                             const float* __restrict__ truths, float* __restrict__ F,
                             int P) {
    int n = blockIdx.y;
    int p = blockIdx.x * blockDim.x + threadIdx.x;
    __shared__ float tr[64];
    if (threadIdx.x < 64) tr[threadIdx.x] = truths[n * 64 + threadIdx.x];
    __syncthreads();
    if (p >= P) return;
    float4 pr = *(const float4*)(priors + (size_t)p * 4);
    float4 l  = *(const float4*)(loc + ((size_t)n * P + p) * 4);
    float cx = pr.x + l.x * 0.1f * pr.z;
    float cy = pr.y + l.y * 0.1f * pr.w;
    float w  = pr.z * fexp2(l.z * 0.2f * LOG2E);
    float h  = pr.w * fexp2(l.w * 0.2f * LOG2E);
    float bx1 = cx - w * 0.5f, by1 = cy - h * 0.5f;
    float bx2 = cx + w * 0.5f, by2 = cy + h * 0.5f;
    float v[16];
    float m = -1.0f;
    #pragma unroll
    for (int o = 0; o < 16; o++) {
        v[o] = iou_xyxy(tr[o * 4], tr[o * 4 + 1], tr[o * 4 + 2], tr[o * 4 + 3],
                        bx1, by1, bx2, by2);
        m = fmaxf(m, v[o]);
    }
    size_t base = ((size_t)n * 16) * P + p;
    #pragma unroll
    for (int o = 0; o < 16; o++) {
        F[base + (size_t)o * P] = (v[o] == m) ? v[o] : 0.0f;
    }
}

// ---------- K2/K5: single-pass per-row top-15 + boost ----------
__global__ __launch_bounds__(256) void k_topk_boost(float* __restrict__ F, int P) {
    int row = blockIdx.x;
    float* R = F + (size_t)row * P;
    int tid = threadIdx.x;

    float lv[TOPK];
    int   li[TOPK];
    #pragma unroll
    for (int k = 0; k < TOPK; k++) { lv[k] = -1.0f; li[k] = 0x7FFFFFFF; }

    int nf4 = P >> 2;
    const float4* R4 = (const float4*)R;
    for (int f = tid; f < nf4; f += 256) {
        float4 q = R4[f];
        float vals[4] = {q.x, q.y, q.z, q.w};
        #pragma unroll
        for (int j = 0; j < 4; j++) {
            float v = vals[j];
            if (v > lv[TOPK - 1]) {
                int i = 4 * f + j;
                #pragma unroll
                for (int k = TOPK - 1; k >= 0; k--) {
                    bool shift = (k > 0) && (v > lv[k - 1]);
                    if (shift)            { lv[k] = lv[k - 1]; li[k] = li[k - 1]; }
                    else if (v > lv[k])   { lv[k] = v;         li[k] = i; }
                }
            }
        }
    }
    for (int i = (nf4 << 2) + tid; i < P; i += 256) {
        float v = R[i];
        if (v > lv[TOPK - 1]) {
            #pragma unroll
            for (int k = TOPK - 1; k >= 0; k--) {
                bool shift = (k > 0) && (v > lv[k - 1]);
                if (shift)          { lv[k] = lv[k - 1]; li[k] = li[k - 1]; }
                else if (v > lv[k]) { lv[k] = v;         li[k] = i; }
            }
        }
    }

    __shared__ unsigned long long cand[256 * TOPK];   // 30 KB
    #pragma unroll
    for (int k = 0; k < TOPK; k++) {
        unsigned long long key = 0ULL;
        if (lv[k] >= 0.0f) {
            unsigned int fb = __float_as_uint(lv[k]);
            key = ((unsigned long long)fb << 32) | (unsigned int)(~(unsigned int)li[k]);
        }
        cand[tid * TOPK + k] = key;
    }
    __syncthreads();

    __shared__ unsigned long long wmax[4];
    __shared__ unsigned long long selKey[TOPK];
    __shared__ int s_num;

    int hp = 0;
    for (int k = 0; k < TOPK; k++) {
        unsigned long long prop = (hp < TOPK) ? cand[tid * TOPK + hp] : 0ULL;
        unsigned long long m = prop;
        #pragma unroll
        for (int s = 32; s > 0; s >>= 1) {
            unsigned long long o = __shfl_down(m, s, 64);
            if (o > m) m = o;
        }
        if ((tid & 63) == 0) wmax[tid >> 6] = m;
        __syncthreads();
        if (tid == 0) {
            unsigned long long w = wmax[0];
            if (wmax[1] > w) w = wmax[1];
            if (wmax[2] > w) w = wmax[2];
            if (wmax[3] > w) w = wmax[3];
            selKey[k] = w;
        }
        __syncthreads();
        unsigned long long w = selKey[k];
        if (w != 0ULL && prop == w) hp++;
    }

    if (tid == 0) {
        float s = 0.0f;
        #pragma unroll
        for (int k = 0; k < TOPK; k++)
            s += __uint_as_float((unsigned int)(selKey[k] >> 32));
        int np = (int)s;
        if (np < 1) np = 1;
        s_num = np;
    }
    __syncthreads();
    if (tid < TOPK && tid < s_num) {
        unsigned long long w = selKey[tid];
        if (w != 0ULL) {
            int idx = (int)(~(unsigned int)(w & 0xFFFFFFFFull));
            float v = __uint_as_float((unsigned int)(w >> 32));
            R[idx] = v + 3.0f;
        }
    }
}

// ---------- K3: reg column pass ----------
__global__ void k_col_reg(const float* __restrict__ F, const int* __restrict__ labels,
                          float* __restrict__ overlap, int* __restrict__ confcls,
                          unsigned int* __restrict__ posCount, int P) {
    int n = blockIdx.y;
    int p = blockIdx.x * blockDim.x + threadIdx.x;
    __shared__ int lab[16];
    if (threadIdx.x < 16) lab[threadIdx.x] = labels[n * 16 + threadIdx.x];
    __syncthreads();
    bool active = (p < P);
    float m = -1.0f; int best = 0;
    if (active) {
        const float* col = F + ((size_t)n * 16) * P + p;
        #pragma unroll
        for (int o = 0; o < 16; o++) {
            float v = col[(size_t)o * P];
            if (v > m) { m = v; best = o; }
        }
        overlap[(size_t)n * P + p] = m;
        confcls[(size_t)n * P + p] = lab[best];
    }
    unsigned long long mask = __ballot(active && (m > 3.0f));
    if ((threadIdx.x & 63) == 0 && mask) atomicAdd(posCount, (unsigned int)__popcll(mask));
}

// ---------- K4: fused conf pass, 2D wave mapping (16 rows x 4 sub-lanes) ----------
// Each 64B line of conf_data is consumed by 4 lanes in one instruction; the
// label gather is fused into the stream via a per-n class->object bitmask LUT.
__global__ __launch_bounds__(256) void k_conf(
        const float* __restrict__ conf, const float* __restrict__ priors,
        const float* __restrict__ truths, const int* __restrict__ labels,
        const float* __restrict__ overlap, const int* __restrict__ confcls,
        float* __restrict__ F, double* __restrict__ accC,
        int P, int C) {
    int n = blockIdx.y;
    __shared__ float strt[64];
    __shared__ unsigned int smask[80];
    if (threadIdx.x < 64) strt[threadIdx.x] = truths[n * 64 + threadIdx.x];
    if (threadIdx.x < 80) smask[threadIdx.x] = 0u;
    __syncthreads();
    if (threadIdx.x < 16) atomicOr(&smask[labels[n * 16 + threadIdx.x]], 1u << threadIdx.x);
    __syncthreads();

    int lane = threadIdx.x & 63;
    int wv   = threadIdx.x >> 6;
    int r    = lane >> 2;        // row within wave (0..15)
    int sub  = lane & 3;         // sub-lane (0..3)
    int p    = blockIdx.x * 64 + wv * 16 + r;
    bool act = (p < P);

    float lsum = 0.0f;
    float pv[16];
    #pragma unroll
    for (int o = 0; o < 16; o++) pv[o] = 0.0f;

    if (act) {
        // prior box (broadcast across the 4 sub-lanes of a row)
        float4 pr = *(const float4*)(priors + (size_t)p * 4);
        float px1 = pr.x - pr.z * 0.5f, py1 = pr.y - pr.w * 0.5f;
        float px2 = pr.x + pr.z * 0.5f, py2 = pr.y + pr.w * 0.5f;
        float ov[16];
        #pragma unroll
        for (int o = 0; o < 16; o++) {
            ov[o] = iou_xyxy(strt[o * 4], strt[o * 4 + 1], strt[o * 4 + 2], strt[o * 4 + 3],
                             px1, py1, px2, py2);
        }

        float ovl = overlap[(size_t)n * P + p];
        int   tc  = (ovl > 1.0f) ? confcls[(size_t)n * P + p] : -1;
        float vt  = fmaxf(ovl - 3.0f, 0.0f);

        const float* rp = conf + ((size_t)n * P + p) * (size_t)C + sub * 4;
        #pragma unroll
        for (int k = 0; k < 5; k++) {
            float4 l4 = *(const float4*)(rp + k * 16);
            float lvv[4] = {l4.x, l4.y, l4.z, l4.w};
            #pragma unroll
            for (int j = 0; j < 4; j++) {
                int   c  = k * 16 + sub * 4 + j;
                float lg = lvv[j];
                // gfocal
                float t  = (c == tc) ? vt : 0.0f;
                float e  = fexp2(-fabsf(lg) * LOG2E);
                float ln1pe = flog2(1.0f + e) * LN2;
                float rc = frcp(1.0f + e);
                float sg = (lg >= 0.0f) ? rc : e * rc;
                float bce = fmaxf(lg, 0.0f) - lg * t + ln1pe;
                float d  = sg - t;
                lsum += d * d * bce;
                // fused label gather -> pred matrix entries
                unsigned int m16 = smask[c];
                if (m16) {
                    float pc = sg;
                    #pragma unroll
                    for (int o = 0; o < 16; o++) {
                        if (m16 & (1u << o)) {
                            pv[o] = (ov[o] > 0.0f)
                                  ? fexp2((2.0f - pc) * 0.5f * flog2(ov[o]))
                                  : 0.0f;
                        }
                    }
                }
            }
        }
    }

    // combine pv across the 4 sub-lanes of each row (at most one lane set each o)
    #pragma unroll
    for (int o = 0; o < 16; o++) {
        pv[o] = fmaxf(pv[o], __shfl_xor(pv[o], 1, 64));
        pv[o] = fmaxf(pv[o], __shfl_xor(pv[o], 2, 64));
    }
    float m = pv[0];
    #pragma unroll
    for (int o = 1; o < 16; o++) m = fmaxf(m, pv[o]);

    if (act) {
        #pragma unroll
        for (int jj = 0; jj < 4; jj++) {
            float val = (sub == 0) ? pv[0 + jj]
                      : (sub == 1) ? pv[4 + jj]
                      : (sub == 2) ? pv[8 + jj]
                                   : pv[12 + jj];
            int o = sub * 4 + jj;
            F[((size_t)(n * 16 + o)) * P + p] = (val == m) ? val : 0.0f;
        }
    }

    // block reduce gfocal partial sums
    double dv = (double)lsum;
    for (int s = 32; s > 0; s >>= 1) dv += __shfl_down(dv, s, 64);
    __shared__ double bsum[4];
    if ((threadIdx.x & 63) == 0) bsum[wv] = dv;
    __syncthreads();
    if (threadIdx.x == 0) {
        double tot = bsum[0] + bsum[1] + bsum[2] + bsum[3];
        atomicAdd(accC, tot);
    }
}

// ---------- K6: pred column pass ----------
__global__ void k_col_pred(const float* __restrict__ F, const float* __restrict__ loc,
                           const float* __restrict__ priors, const float* __restrict__ truths,
                           double* __restrict__ accL, double* __restrict__ accR, int P) {
    int n = blockIdx.y;
    int p = blockIdx.x * blockDim.x + threadIdx.x;
    __shared__ float strt[64];
    if (threadIdx.x < 64) strt[threadIdx.x] = truths[n * 64 + threadIdx.x];
    __syncthreads();

    float r = 0.0f, contrib = 0.0f;
    if (p < P) {
        const float* col = F + ((size_t)n * 16) * P + p;
        float m = -1.0f; int best = 0;
        #pragma unroll
        for (int o = 0; o < 16; o++) {
            float v = col[(size_t)o * P];
            if (v > m) { m = v; best = o; }
        }
        r = fmaxf(m - 3.0f, 0.0f);
        if (r > 0.0f) {
            const float Bc   = (float)19.085536923187668;
            const float beta = 0.11f;
            float4 pr = *(const float4*)(priors + (size_t)p * 4);
            float tx1 = strt[best * 4],     ty1 = strt[best * 4 + 1];
            float tx2 = strt[best * 4 + 2], ty2 = strt[best * 4 + 3];
            float gcx = ((tx1 + tx2) * 0.5f - pr.x) / (0.1f * pr.z);
            float gcy = ((ty1 + ty2) * 0.5f - pr.y) / (0.1f * pr.w);
            float gw  = flog2((tx2 - tx1) / pr.z) * LN2 / 0.2f;
            float gh  = flog2((ty2 - ty1) / pr.w) * LN2 / 0.2f;
            float4 l  = *(const float4*)(loc + ((size_t)n * P + p) * 4);
            float tgt[4] = {gcx, gcy, gw, gh};
            float lvv[4] = {l.x, l.y, l.z, l.w};
            float s = 0.0f;
            #pragma unroll
            for (int j = 0; j < 4; j++) {
                float diff = fabsf(lvv[j] - tgt[j]);
                float bl;
                if (diff < beta) {
                    bl = 0.5f / Bc * (Bc * diff + 1.0f) * (flog2(1.0f + Bc * diff / beta) * LN2)
                         - 0.5f * diff;
                } else {
                    bl = 1.5f * diff + 1.5f / Bc - 0.5f * beta;
                }
                s += bl;
            }
            contrib = r * s;
        }
    }
    double dl = (double)contrib, dr = (double)r;
    for (int s = 32; s > 0; s >>= 1) { dl += __shfl_down(dl, s, 64); dr += __shfl_down(dr, s, 64); }
    __shared__ double bl_[4], br_[4];
    int wid = threadIdx.x >> 6;
    if ((threadIdx.x & 63) == 0) { bl_[wid] = dl; br_[wid] = dr; }
    __syncthreads();
    if (threadIdx.x == 0) {
        double tl  = bl_[0] + bl_[1] + bl_[2] + bl_[3];
        double tr2 = br_[0] + br_[1] + br_[2] + br_[3];
        atomicAdd(accL, tl);
        atomicAdd(accR, tr2);
    }
}

// ---------- K7: finalize ----------
__global__ void k_final(const double* accC, const double* accL, const double* accR,
                        const unsigned int* posCount, float* out) {
    if (threadIdx.x == 0) {
        unsigned int pc = *posCount;
        double npos = (double)(pc > 0u ? pc : 1u);
        double denom = 4.0 * (*accR);
        out[0] = (float)((*accL) / denom);
        out[1] = (float)((*accC) / npos);
    }
}

extern "C" void kernel_launch(void* const* d_in, const int* in_sizes, int n_in,
                              void* d_out, int out_size, void* d_ws, size_t ws_size,
                              hipStream_t stream) {
    const float* loc    = (const float*)d_in[0];
    const float* conf   = (const float*)d_in[1];
    const float* priors = (const float*)d_in[2];
    const float* truths = (const float*)d_in[3];
    const int*   labels = (const int*)d_in[4];

    int P = in_sizes[2] / 4;                 // 18000
    int N = in_sizes[0] / (P * 4);           // 32
    int C = in_sizes[1] / (N * P);           // 80

    char* ws = (char*)d_ws;
    double* accC = (double*)ws;
    double* accL = accC + 1;
    double* accR = accC + 2;
    unsigned int* posCount = (unsigned int*)(accC + 3);
    float* F       = (float*)(ws + 64);
    float* overlap = F + (size_t)N * 16 * P;
    int*   confcls = (int*)(overlap + (size_t)N * P);
    float* out = (float*)d_out;

    dim3 blk(256);
    dim3 gridP((P + 255) / 256, N);
    dim3 gridC((P + 63) / 64, N);

    k_zero<<<1, 64, 0, stream>>>(accC, accL, accR, posCount);
    k_reg_matrix<<<gridP, blk, 0, stream>>>(loc, priors, truths, F, P);
    k_topk_boost<<<N * 16, blk, 0, stream>>>(F, P);
    k_col_reg<<<gridP, blk, 0, stream>>>(F, labels, overlap, confcls, posCount, P);
    k_conf<<<gridC, blk, 0, stream>>>(conf, priors, truths, labels, overlap, confcls,
                                      F, accC, P, C);
    k_topk_boost<<<N * 16, blk, 0, stream>>>(F, P);
    k_col_pred<<<gridP, blk, 0, stream>>>(F, loc, priors, truths, accL, accR, P);
    k_final<<<1, 1, 0, stream>>>(accC, accL, accR, posCount, out);
}

// Round 5
// 346.183 us; speedup vs baseline: 5.6425x; 1.0192x over previous
//
#include <hip/hip_runtime.h>
#include <hip/hip_bf16.h>

#define TOPK 15
#define LOG2E 1.44269504088896340736f
#define LN2   0.69314718055994530942f

// ---------- fast math ----------
__device__ __forceinline__ float fexp2(float x) { return __builtin_amdgcn_exp2f(x); }
__device__ __forceinline__ float flog2(float x) { return __builtin_amdgcn_logf(x); }
__device__ __forceinline__ float frcp(float x)  { return __builtin_amdgcn_rcpf(x); }
__device__ __forceinline__ float fsigmoid(float x) {
    float e = fexp2(-fabsf(x) * LOG2E);
    float r = frcp(1.0f + e);
    return x >= 0.0f ? r : e * r;
}

// ---------- helpers ----------
__device__ __forceinline__ float iou_xyxy(float ax1, float ay1, float ax2, float ay2,
                                          float bx1, float by1, float bx2, float by2) {
    float ltx = fmaxf(ax1, bx1), lty = fmaxf(ay1, by1);
    float rbx = fminf(ax2, bx2), rby = fminf(ay2, by2);
    float w = fmaxf(rbx - ltx, 0.0f), h = fmaxf(rby - lty, 0.0f);
    float inter = w * h;
    float areaA = (ax2 - ax1) * (ay2 - ay1);
    float areaB = (bx2 - bx1) * (by2 - by1);
    return inter / (areaA + areaB - inter);
}

// ---------- K0 ----------
__global__ void k_zero(double* accC, double* accL, double* accR, unsigned int* posCount) {
    if (threadIdx.x == 0) {
        *accC = 0.0; *accL = 0.0; *accR = 0.0; *posCount = 0u;
    }
}

// ---------- K1: reg matrix ----------
__global__ void k_reg_matrix(const float* __restrict__ loc, const float* __restrict__ priors,
                             const float* __restrict__ truths, float* __restrict__ F,
                             int P) {
    int n = blockIdx.y;
    int p = blockIdx.x * blockDim.x + threadIdx.x;
    __shared__ float tr[64];
    if (threadIdx.x < 64) tr[threadIdx.x] = truths[n * 64 + threadIdx.x];
    __syncthreads();
    if (p >= P) return;
    float4 pr = *(const float4*)(priors + (size_t)p * 4);
    float4 l  = *(const float4*)(loc + ((size_t)n * P + p) * 4);
    float cx = pr.x + l.x * 0.1f * pr.z;
    float cy = pr.y + l.y * 0.1f * pr.w;
    float w  = pr.z * fexp2(l.z * 0.2f * LOG2E);
    float h  = pr.w * fexp2(l.w * 0.2f * LOG2E);
    float bx1 = cx - w * 0.5f, by1 = cy - h * 0.5f;
    float bx2 = cx + w * 0.5f, by2 = cy + h * 0.5f;
    float v[16];
    float m = -1.0f;
    #pragma unroll
    for (int o = 0; o < 16; o++) {
        v[o] = iou_xyxy(tr[o * 4], tr[o * 4 + 1], tr[o * 4 + 2], tr[o * 4 + 3],
                        bx1, by1, bx2, by2);
        m = fmaxf(m, v[o]);
    }
    size_t base = ((size_t)n * 16) * P + p;
    #pragma unroll
    for (int o = 0; o < 16; o++) {
        F[base + (size_t)o * P] = (v[o] == m) ? v[o] : 0.0f;
    }
}

// ---------- K2/K5: single-pass per-row top-15 + boost ----------
__global__ __launch_bounds__(256) void k_topk_boost(float* __restrict__ F, int P) {
    int row = blockIdx.x;
    float* R = F + (size_t)row * P;
    int tid = threadIdx.x;

    float lv[TOPK];
    int   li[TOPK];
    #pragma unroll
    for (int k = 0; k < TOPK; k++) { lv[k] = -1.0f; li[k] = 0x7FFFFFFF; }

    int nf4 = P >> 2;
    const float4* R4 = (const float4*)R;
    for (int f = tid; f < nf4; f += 256) {
        float4 q = R4[f];
        float vals[4] = {q.x, q.y, q.z, q.w};
        #pragma unroll
        for (int j = 0; j < 4; j++) {
            float v = vals[j];
            if (v > lv[TOPK - 1]) {
                int i = 4 * f + j;
                #pragma unroll
                for (int k = TOPK - 1; k >= 0; k--) {
                    bool shift = (k > 0) && (v > lv[k - 1]);
                    if (shift)            { lv[k] = lv[k - 1]; li[k] = li[k - 1]; }
                    else if (v > lv[k])   { lv[k] = v;         li[k] = i; }
                }
            }
        }
    }
    for (int i = (nf4 << 2) + tid; i < P; i += 256) {
        float v = R[i];
        if (v > lv[TOPK - 1]) {
            #pragma unroll
            for (int k = TOPK - 1; k >= 0; k--) {
                bool shift = (k > 0) && (v > lv[k - 1]);
                if (shift)          { lv[k] = lv[k - 1]; li[k] = li[k - 1]; }
                else if (v > lv[k]) { lv[k] = v;         li[k] = i; }
            }
        }
    }

    __shared__ unsigned long long cand[256 * TOPK];   // 30 KB
    #pragma unroll
    for (int k = 0; k < TOPK; k++) {
        unsigned long long key = 0ULL;
        if (lv[k] >= 0.0f) {
            unsigned int fb = __float_as_uint(lv[k]);
            key = ((unsigned long long)fb << 32) | (unsigned int)(~(unsigned int)li[k]);
        }
        cand[tid * TOPK + k] = key;
    }
    __syncthreads();

    __shared__ unsigned long long wmax[4];
    __shared__ unsigned long long selKey[TOPK];
    __shared__ int s_num;

    int hp = 0;
    for (int k = 0; k < TOPK; k++) {
        unsigned long long prop = (hp < TOPK) ? cand[tid * TOPK + hp] : 0ULL;
        unsigned long long m = prop;
        #pragma unroll
        for (int s = 32; s > 0; s >>= 1) {
            unsigned long long o = __shfl_down(m, s, 64);
            if (o > m) m = o;
        }
        if ((tid & 63) == 0) wmax[tid >> 6] = m;
        __syncthreads();
        if (tid == 0) {
            unsigned long long w = wmax[0];
            if (wmax[1] > w) w = wmax[1];
            if (wmax[2] > w) w = wmax[2];
            if (wmax[3] > w) w = wmax[3];
            selKey[k] = w;
        }
        __syncthreads();
        unsigned long long w = selKey[k];
        if (w != 0ULL && prop == w) hp++;
    }

    if (tid == 0) {
        float s = 0.0f;
        #pragma unroll
        for (int k = 0; k < TOPK; k++)
            s += __uint_as_float((unsigned int)(selKey[k] >> 32));
        int np = (int)s;
        if (np < 1) np = 1;
        s_num = np;
    }
    __syncthreads();
    if (tid < TOPK && tid < s_num) {
        unsigned long long w = selKey[tid];
        if (w != 0ULL) {
            int idx = (int)(~(unsigned int)(w & 0xFFFFFFFFull));
            float v = __uint_as_float((unsigned int)(w >> 32));
            R[idx] = v + 3.0f;
        }
    }
}

// ---------- K4: fused conf pass with LDS row staging ----------
// block = 256 threads <-> 64 rows (thread = (row, sub), sub in 0..3).
// Stage conf rows into LDS (stride 84: 2-way bank aliasing only, free).
// Fuses: reg-F column argmax (ex-k_col_reg) + posCount, gfocal (20 classes
// per sub from LDS), pred-matrix build (4 IoU + 4 direct gathers per sub).
__global__ __launch_bounds__(256) void k_conf(
        const float* __restrict__ conf, const float* __restrict__ priors,
        const float* __restrict__ truths, const int* __restrict__ labels,
        float* __restrict__ F, double* __restrict__ accC,
        unsigned int* __restrict__ posCount, int P) {
    int n = blockIdx.y;
    int p0 = blockIdx.x * 64;
    int valid = P - p0; if (valid > 64) valid = 64;

    __shared__ float tile[64 * 84];          // 21504 B
    __shared__ float strt[64];
    __shared__ int   lab[16];
    if (threadIdx.x < 64) strt[threadIdx.x] = truths[n * 64 + threadIdx.x];
    if (threadIdx.x < 16) lab[threadIdx.x]  = labels[n * 16 + threadIdx.x];

    // coalesced staging: 64 rows x 80 floats = 1280 float4
    const float* src = conf + ((size_t)n * P + p0) * 80;
    #pragma unroll
    for (int i = 0; i < 5; i++) {
        int idx4 = threadIdx.x + i * 256;    // 0..1279
        int r    = idx4 / 20;
        int c4   = idx4 - r * 20;
        if (r < valid) {
            float4 v = *(const float4*)(src + (size_t)idx4 * 4);
            *(float4*)(&tile[r * 84 + c4 * 4]) = v;
        }
    }
    __syncthreads();

    int tid  = threadIdx.x;
    int r    = tid >> 2;
    int sub  = tid & 3;
    int p    = p0 + r;
    bool act = (p < P);
    const float* myrow = &tile[r * 84];

    // ---- fused reg-F column argmax (first-index tie-break via packed key)
    unsigned long long key = 0ULL;
    #pragma unroll
    for (int jj = 0; jj < 4; jj++) {
        int o = sub * 4 + jj;
        float v = act ? F[((size_t)(n * 16 + o)) * P + p] : 0.0f;
        unsigned long long kk =
            ((unsigned long long)__float_as_uint(v) << 32) | (unsigned int)(~(unsigned int)o);
        if (kk > key) key = kk;
    }
    {
        unsigned long long t1 = __shfl_xor(key, 1, 64); if (t1 > key) key = t1;
        unsigned long long t2 = __shfl_xor(key, 2, 64); if (t2 > key) key = t2;
    }
    float movl = __uint_as_float((unsigned int)(key >> 32));
    int   best = (int)(~(unsigned int)(key & 0xFFFFFFFFull));
    float vt = fmaxf(movl - 3.0f, 0.0f);
    int   tc = (movl > 1.0f) ? lab[best] : -1;

    // posCount: one vote per row (sub==0)
    unsigned long long bm = __ballot(act && sub == 0 && movl > 3.0f);
    if ((tid & 63) == 0 && bm) atomicAdd(posCount, (unsigned int)__popcll(bm));

    // ---- gfocal over this sub-lane's 20 classes (from LDS)
    float lsum = 0.0f;
    if (act) {
        #pragma unroll
        for (int k = 0; k < 5; k++) {
            float4 l4 = *(const float4*)(myrow + sub * 20 + k * 4);
            float lvv[4] = {l4.x, l4.y, l4.z, l4.w};
            #pragma unroll
            for (int j = 0; j < 4; j++) {
                int   c  = sub * 20 + k * 4 + j;
                float lg = lvv[j];
                float t  = (c == tc) ? vt : 0.0f;
                float e  = fexp2(-fabsf(lg) * LOG2E);
                float ln1pe = flog2(1.0f + e) * LN2;
                float rc = frcp(1.0f + e);
                float sg = (lg >= 0.0f) ? rc : e * rc;
                float bce = fmaxf(lg, 0.0f) - lg * t + ln1pe;
                float d  = sg - t;
                lsum += d * d * bce;
            }
        }
    }

    // ---- pred path: 4 IoUs + 4 direct LDS gathers per sub-lane
    float pv[4];
    float pm = 0.0f;
    float px1 = 0, py1 = 0, px2 = 0, py2 = 0;
    if (act) {
        float4 pr = *(const float4*)(priors + (size_t)p * 4);
        px1 = pr.x - pr.z * 0.5f; py1 = pr.y - pr.w * 0.5f;
        px2 = pr.x + pr.z * 0.5f; py2 = pr.y + pr.w * 0.5f;
    }
    #pragma unroll
    for (int jj = 0; jj < 4; jj++) {
        int o = sub * 4 + jj;
        float pd = 0.0f;
        if (act) {
            float ov = iou_xyxy(strt[o * 4], strt[o * 4 + 1], strt[o * 4 + 2], strt[o * 4 + 3],
                                px1, py1, px2, py2);
            if (ov > 0.0f) {
                float pc = fsigmoid(myrow[lab[o]]);
                pd = fexp2((2.0f - pc) * 0.5f * flog2(ov));
            }
        }
        pv[jj] = pd;
        pm = fmaxf(pm, pd);
    }
    pm = fmaxf(pm, __shfl_xor(pm, 1, 64));
    pm = fmaxf(pm, __shfl_xor(pm, 2, 64));
    if (act) {
        #pragma unroll
        for (int jj = 0; jj < 4; jj++) {
            int o = sub * 4 + jj;
            F[((size_t)(n * 16 + o)) * P + p] = (pv[jj] == pm) ? pv[jj] : 0.0f;
        }
    }

    // ---- block reduce gfocal partials
    #pragma unroll
    for (int s = 32; s > 0; s >>= 1) lsum += __shfl_down(lsum, s, 64);
    __shared__ float wsum[4];
    if ((tid & 63) == 0) wsum[tid >> 6] = lsum;
    __syncthreads();
    if (tid == 0) {
        double tot = (double)wsum[0] + (double)wsum[1] + (double)wsum[2] + (double)wsum[3];
        atomicAdd(accC, tot);
    }
}

// ---------- K6: pred column pass ----------
__global__ void k_col_pred(const float* __restrict__ F, const float* __restrict__ loc,
                           const float* __restrict__ priors, const float* __restrict__ truths,
                           double* __restrict__ accL, double* __restrict__ accR, int P) {
    int n = blockIdx.y;
    int p = blockIdx.x * blockDim.x + threadIdx.x;
    __shared__ float strt[64];
    if (threadIdx.x < 64) strt[threadIdx.x] = truths[n * 64 + threadIdx.x];
    __syncthreads();

    float r = 0.0f, contrib = 0.0f;
    if (p < P) {
        const float* col = F + ((size_t)n * 16) * P + p;
        float m = -1.0f; int best = 0;
        #pragma unroll
        for (int o = 0; o < 16; o++) {
            float v = col[(size_t)o * P];
            if (v > m) { m = v; best = o; }
        }
        r = fmaxf(m - 3.0f, 0.0f);
        if (r > 0.0f) {
            const float Bc   = (float)19.085536923187668;
            const float beta = 0.11f;
            float4 pr = *(const float4*)(priors + (size_t)p * 4);
            float tx1 = strt[best * 4],     ty1 = strt[best * 4 + 1];
            float tx2 = strt[best * 4 + 2], ty2 = strt[best * 4 + 3];
            float gcx = ((tx1 + tx2) * 0.5f - pr.x) / (0.1f * pr.z);
            float gcy = ((ty1 + ty2) * 0.5f - pr.y) / (0.1f * pr.w);
            float gw  = flog2((tx2 - tx1) / pr.z) * LN2 / 0.2f;
            float gh  = flog2((ty2 - ty1) / pr.w) * LN2 / 0.2f;
            float4 l  = *(const float4*)(loc + ((size_t)n * P + p) * 4);
            float tgt[4] = {gcx, gcy, gw, gh};
            float lvv[4] = {l.x, l.y, l.z, l.w};
            float s = 0.0f;
            #pragma unroll
            for (int j = 0; j < 4; j++) {
                float diff = fabsf(lvv[j] - tgt[j]);
                float bl;
                if (diff < beta) {
                    bl = 0.5f / Bc * (Bc * diff + 1.0f) * (flog2(1.0f + Bc * diff / beta) * LN2)
                         - 0.5f * diff;
                } else {
                    bl = 1.5f * diff + 1.5f / Bc - 0.5f * beta;
                }
                s += bl;
            }
            contrib = r * s;
        }
    }
    double dl = (double)contrib, dr = (double)r;
    for (int s = 32; s > 0; s >>= 1) { dl += __shfl_down(dl, s, 64); dr += __shfl_down(dr, s, 64); }
    __shared__ double bl_[4], br_[4];
    int wid = threadIdx.x >> 6;
    if ((threadIdx.x & 63) == 0) { bl_[wid] = dl; br_[wid] = dr; }
    __syncthreads();
    if (threadIdx.x == 0) {
        double tl  = bl_[0] + bl_[1] + bl_[2] + bl_[3];
        double tr2 = br_[0] + br_[1] + br_[2] + br_[3];
        atomicAdd(accL, tl);
        atomicAdd(accR, tr2);
    }
}

// ---------- K7: finalize ----------
__global__ void k_final(const double* accC, const double* accL, const double* accR,
                        const unsigned int* posCount, float* out) {
    if (threadIdx.x == 0) {
        unsigned int pc = *posCount;
        double npos = (double)(pc > 0u ? pc : 1u);
        double denom = 4.0 * (*accR);
        out[0] = (float)((*accL) / denom);
        out[1] = (float)((*accC) / npos);
    }
}

extern "C" void kernel_launch(void* const* d_in, const int* in_sizes, int n_in,
                              void* d_out, int out_size, void* d_ws, size_t ws_size,
                              hipStream_t stream) {
    const float* loc    = (const float*)d_in[0];
    const float* conf   = (const float*)d_in[1];
    const float* priors = (const float*)d_in[2];
    const float* truths = (const float*)d_in[3];
    const int*   labels = (const int*)d_in[4];

    int P = in_sizes[2] / 4;                 // 18000
    int N = in_sizes[0] / (P * 4);           // 32
    // C == 80 assumed by k_conf's tiling

    char* ws = (char*)d_ws;
    double* accC = (double*)ws;
    double* accL = accC + 1;
    double* accR = accC + 2;
    unsigned int* posCount = (unsigned int*)(accC + 3);
    float* F = (float*)(ws + 64);            // N*16*P floats
    float* out = (float*)d_out;

    dim3 blk(256);
    dim3 gridP((P + 255) / 256, N);
    dim3 gridC((P + 63) / 64, N);

    k_zero<<<1, 64, 0, stream>>>(accC, accL, accR, posCount);
    k_reg_matrix<<<gridP, blk, 0, stream>>>(loc, priors, truths, F, P);
    k_topk_boost<<<N * 16, blk, 0, stream>>>(F, P);
    k_conf<<<gridC, blk, 0, stream>>>(conf, priors, truths, labels, F, accC, posCount, P);
    k_topk_boost<<<N * 16, blk, 0, stream>>>(F, P);
    k_col_pred<<<gridP, blk, 0, stream>>>(F, loc, priors, truths, accL, accR, P);
    k_final<<<1, 1, 0, stream>>>(accC, accL, accR, posCount, out);
}

// Round 6
// 331.427 us; speedup vs baseline: 5.8937x; 1.0445x over previous
//
#include <hip/hip_runtime.h>
#include <hip/hip_bf16.h>

typedef unsigned long long u64;
typedef unsigned int u32;

#define LOG2E 1.44269504088896340736f
#define LN2   0.69314718055994530942f

// ---------- fast math ----------
__device__ __forceinline__ float fexp2(float x) { return __builtin_amdgcn_exp2f(x); }
__device__ __forceinline__ float flog2(float x) { return __builtin_amdgcn_logf(x); }
__device__ __forceinline__ float frcp(float x)  { return __builtin_amdgcn_rcpf(x); }
__device__ __forceinline__ float fsigmoid(float x) {
    float e = fexp2(-fabsf(x) * LOG2E);
    float r = frcp(1.0f + e);
    return x >= 0.0f ? r : e * r;
}
__device__ __forceinline__ float keyval(u64 k) { return __uint_as_float((u32)(k >> 32)); }

__device__ __forceinline__ float iou_xyxy(float ax1, float ay1, float ax2, float ay2,
                                          float bx1, float by1, float bx2, float by2) {
    float ltx = fmaxf(ax1, bx1), lty = fmaxf(ay1, by1);
    float rbx = fminf(ax2, bx2), rby = fminf(ay2, by2);
    float w = fmaxf(rbx - ltx, 0.0f), h = fmaxf(rby - lty, 0.0f);
    float inter = w * h;
    float areaA = (ax2 - ax1) * (ay2 - ay1);
    float areaB = (bx2 - bx1) * (by2 - by1);
    return inter / (areaA + areaB - inter);
}

__device__ __forceinline__ void csw(u64& a, u64& b) { if (a < b) { u64 t = a; a = b; b = t; } }

// Per-block per-row top-15: fkey is [16][65] u64 in LDS (keys unique, 0=empty).
// 16 teams of 16 lanes; each lane holds 4 sorted keys; 15 tournament rounds.
// Writes 15 keys (value desc, index asc via ~p) to cand[(rowbase+o)*NBLK+blk].
__device__ __forceinline__ void row_top15(const u64* fkey, u64* cand, size_t rowbase,
                                          int blk, int NBLK, int tid) {
    int o = tid >> 4, l16 = tid & 15;
    const u64* rk = fkey + o * 65;
    u64 k0 = rk[l16 * 4], k1 = rk[l16 * 4 + 1], k2 = rk[l16 * 4 + 2], k3 = rk[l16 * 4 + 3];
    csw(k0, k1); csw(k2, k3); csw(k0, k2); csw(k1, k3); csw(k1, k2);
    u64 w = 0;
    #pragma unroll
    for (int j = 0; j < 15; j++) {
        u64 m = k0;
        #pragma unroll
        for (int s = 8; s >= 1; s >>= 1) { u64 t = __shfl_xor(m, s, 16); if (t > m) m = t; }
        if (k0 == m) { k0 = k1; k1 = k2; k2 = k3; k3 = 0; }
        if (l16 == j) w = m;
    }
    if (l16 < 15) {
        u64* out = cand + ((rowbase + (size_t)o) * (size_t)NBLK + blk) * 15;
        out[l16] = w;
    }
}

// ---------- K0 ----------
__global__ void k_zero(double* accC, double* accL, double* accR, unsigned int* posCount) {
    if (threadIdx.x == 0) { *accC = 0.0; *accL = 0.0; *accR = 0.0; *posCount = 0u; }
}

// ---------- K1: reg path -> ovkey base + per-block top15 candidates ----------
__global__ __launch_bounds__(256) void k_reg(
        const float* __restrict__ loc, const float* __restrict__ priors,
        const float* __restrict__ truths, u64* __restrict__ ovkey,
        u64* __restrict__ cand, int P, int NBLK) {
    int n = blockIdx.y, p0 = blockIdx.x * 64, tid = threadIdx.x;
    __shared__ float strt[64];
    __shared__ u64 fkey[16 * 65];
    if (tid < 64) strt[tid] = truths[n * 64 + tid];
    __syncthreads();
    int r = tid >> 2, sub = tid & 3, p = p0 + r;
    bool act = p < P;
    float vv[4] = {0, 0, 0, 0};
    u64 mykey = 0;
    if (act) {
        float4 pr = *(const float4*)(priors + (size_t)p * 4);
        float4 l  = *(const float4*)(loc + ((size_t)n * P + p) * 4);
        float cx = pr.x + l.x * 0.1f * pr.z;
        float cy = pr.y + l.y * 0.1f * pr.w;
        float w  = pr.z * fexp2(l.z * 0.2f * LOG2E);
        float h  = pr.w * fexp2(l.w * 0.2f * LOG2E);
        float bx1 = cx - w * 0.5f, by1 = cy - h * 0.5f;
        float bx2 = cx + w * 0.5f, by2 = cy + h * 0.5f;
        #pragma unroll
        for (int jj = 0; jj < 4; jj++) {
            int o = sub * 4 + jj;
            float v = iou_xyxy(strt[o * 4], strt[o * 4 + 1], strt[o * 4 + 2], strt[o * 4 + 3],
                               bx1, by1, bx2, by2);
            vv[jj] = v;
            u64 kk = ((u64)__float_as_uint(v) << 32) | (u32)(~(u32)o);
            if (kk > mykey) mykey = kk;
        }
    }
    { u64 t = __shfl_xor(mykey, 1, 64); if (t > mykey) mykey = t;
      t = __shfl_xor(mykey, 2, 64); if (t > mykey) mykey = t; }
    float m = keyval(mykey);
    if (act && sub == 0) ovkey[(size_t)n * P + p] = mykey;
    #pragma unroll
    for (int jj = 0; jj < 4; jj++) {
        int o = sub * 4 + jj;
        u64 kk = 0;
        if (act) kk = ((vv[jj] == m) ? ((u64)__float_as_uint(m) << 32) : 0ULL) | (u32)(~(u32)p);
        fkey[o * 65 + r] = kk;
    }
    __syncthreads();
    row_top15(fkey, cand, (size_t)n * 16, blockIdx.x, NBLK, tid);
}

// ---------- K2/K4: merge per-block top15 lists -> global top15, apply boosts ----------
__global__ __launch_bounds__(256) void k_merge_boost(
        const u64* __restrict__ cand, u64* __restrict__ keyarr, int P, int NBLK) {
    extern __shared__ u64 sk[];
    int row = blockIdx.x, tid = threadIdx.x;
    int n = row >> 4, o = row & 15;
    int total = NBLK * 15;
    const u64* src = cand + (size_t)row * total;
    for (int i = tid; i < total; i += 256) sk[i] = src[i];
    __syncthreads();
    int l0 = tid, l1 = tid + 256;
    int h0 = 0, h1 = 0;
    __shared__ u64 wm[4];
    __shared__ u64 selk[15];
    __shared__ int snum;
    for (int j = 0; j < 15; j++) {
        u64 q0 = (l0 < NBLK && h0 < 15) ? sk[l0 * 15 + h0] : 0ULL;
        u64 q1 = (l1 < NBLK && h1 < 15) ? sk[l1 * 15 + h1] : 0ULL;
        u64 pr = q0 > q1 ? q0 : q1;
        u64 m = pr;
        #pragma unroll
        for (int s = 32; s >= 1; s >>= 1) { u64 t = __shfl_xor(m, s, 64); if (t > m) m = t; }
        if ((tid & 63) == 0) wm[tid >> 6] = m;
        __syncthreads();
        m = wm[0]; if (wm[1] > m) m = wm[1]; if (wm[2] > m) m = wm[2]; if (wm[3] > m) m = wm[3];
        if (m != 0ULL) {
            if (q0 == m) h0++; else if (q1 == m) h1++;
        }
        if (tid == 0) selk[j] = m;
        __syncthreads();
    }
    if (tid == 0) {
        float s = 0.0f;
        #pragma unroll
        for (int j = 0; j < 15; j++) s += keyval(selk[j]);
        int np = (int)s; if (np < 1) np = 1;
        snum = np;
    }
    __syncthreads();
    if (tid < 15 && tid < snum) {
        u64 k = selk[tid];
        u32 pidx = ~(u32)(k & 0xFFFFFFFFULL);
        if (pidx < (u32)P) {
            float v = keyval(k) + 3.0f;
            u64 bk = ((u64)__float_as_uint(v) << 32) | (u32)(~(u32)o);
            atomicMax(&keyarr[(size_t)n * P + pidx], bk);
        }
    }
}

// ---------- K3: fused conf pass (gfocal + posCount + pred base/cands) ----------
__global__ __launch_bounds__(256) void k_conf(
        const float* __restrict__ conf, const float* __restrict__ priors,
        const float* __restrict__ truths, const int* __restrict__ labels,
        const u64* __restrict__ ovkey, u64* __restrict__ predkey,
        u64* __restrict__ cand, double* __restrict__ accC,
        unsigned int* __restrict__ posCount, int P, int NBLK) {
    int n = blockIdx.y, p0 = blockIdx.x * 64, tid = threadIdx.x;
    int valid = P - p0; if (valid > 64) valid = 64;
    __shared__ __align__(16) float tile[64 * 84];   // aliased by fkey after pred phase
    __shared__ float strt[64];
    __shared__ int lab[16];
    if (tid < 64) strt[tid] = truths[n * 64 + tid];
    if (tid < 16) lab[tid]  = labels[n * 16 + tid];
    const float* src = conf + ((size_t)n * P + p0) * 80;
    #pragma unroll
    for (int i = 0; i < 5; i++) {
        int idx4 = tid + i * 256;
        int rr = idx4 / 20, c4 = idx4 - rr * 20;
        if (rr < valid) {
            float4 v = *(const float4*)(src + (size_t)idx4 * 4);
            *(float4*)(&tile[rr * 84 + c4 * 4]) = v;
        }
    }
    __syncthreads();
    int r = tid >> 2, sub = tid & 3, p = p0 + r;
    bool act = p < P;
    const float* myrow = &tile[r * 84];

    float movl = 0.0f; int best = 0;
    if (act) {
        u64 k = ovkey[(size_t)n * P + p];
        movl = keyval(k);
        best = (int)(~(u32)(k & 0xFFFFFFFFULL)) & 15;
    }
    float vt = fmaxf(movl - 3.0f, 0.0f);
    int tc = (movl > 1.0f) ? lab[best] : -1;
    unsigned long long bm = __ballot(act && sub == 0 && movl > 3.0f);
    if ((tid & 63) == 0 && bm) atomicAdd(posCount, (u32)__popcll(bm));

    float lsum = 0.0f;
    if (act) {
        #pragma unroll
        for (int k5 = 0; k5 < 5; k5++) {
            float4 l4 = *(const float4*)(myrow + sub * 20 + k5 * 4);
            float lvv[4] = {l4.x, l4.y, l4.z, l4.w};
            #pragma unroll
            for (int j = 0; j < 4; j++) {
                int c = sub * 20 + k5 * 4 + j;
                float lg = lvv[j];
                float t  = (c == tc) ? vt : 0.0f;
                float e  = fexp2(-fabsf(lg) * LOG2E);
                float ln1pe = flog2(1.0f + e) * LN2;
                float rc = frcp(1.0f + e);
                float sg = (lg >= 0.0f) ? rc : e * rc;
                float bce = fmaxf(lg, 0.0f) - lg * t + ln1pe;
                float d = sg - t;
                lsum += d * d * bce;
            }
        }
    }

    float pv[4] = {0, 0, 0, 0};
    u64 pkey = 0;
    if (act) {
        float4 pr = *(const float4*)(priors + (size_t)p * 4);
        float px1 = pr.x - pr.z * 0.5f, py1 = pr.y - pr.w * 0.5f;
        float px2 = pr.x + pr.z * 0.5f, py2 = pr.y + pr.w * 0.5f;
        #pragma unroll
        for (int jj = 0; jj < 4; jj++) {
            int o = sub * 4 + jj;
            float ov = iou_xyxy(strt[o * 4], strt[o * 4 + 1], strt[o * 4 + 2], strt[o * 4 + 3],
                                px1, py1, px2, py2);
            float pd = 0.0f;
            if (ov > 0.0f) {
                float pc = fsigmoid(myrow[lab[o]]);
                pd = fexp2((2.0f - pc) * 0.5f * flog2(ov));
            }
            pv[jj] = pd;
            u64 kk = ((u64)__float_as_uint(pd) << 32) | (u32)(~(u32)o);
            if (kk > pkey) pkey = kk;
        }
    }
    { u64 t = __shfl_xor(pkey, 1, 64); if (t > pkey) pkey = t;
      t = __shfl_xor(pkey, 2, 64); if (t > pkey) pkey = t; }
    float pm = keyval(pkey);
    if (act && sub == 0) predkey[(size_t)n * P + p] = pkey;

    __syncthreads();               // tile reads finished; alias as fkey
    u64* fkey = (u64*)tile;
    #pragma unroll
    for (int jj = 0; jj < 4; jj++) {
        int o = sub * 4 + jj;
        u64 kk = 0;
        if (act) kk = ((pv[jj] == pm) ? ((u64)__float_as_uint(pm) << 32) : 0ULL) | (u32)(~(u32)p);
        fkey[o * 65 + r] = kk;
    }
    __syncthreads();
    row_top15(fkey, cand, (size_t)n * 16, blockIdx.x, NBLK, tid);

    #pragma unroll
    for (int s = 32; s > 0; s >>= 1) lsum += __shfl_down(lsum, s, 64);
    __shared__ float wsum[4];
    if ((tid & 63) == 0) wsum[tid >> 6] = lsum;
    __syncthreads();
    if (tid == 0) {
        double tot = (double)wsum[0] + (double)wsum[1] + (double)wsum[2] + (double)wsum[3];
        atomicAdd(accC, tot);
    }
}

// ---------- K5: localization loss from predkey ----------
__global__ __launch_bounds__(256) void k_loss_l(
        const u64* __restrict__ predkey, const float* __restrict__ loc,
        const float* __restrict__ priors, const float* __restrict__ truths,
        double* __restrict__ accL, double* __restrict__ accR, int P) {
    int n = blockIdx.y;
    int p = blockIdx.x * 256 + threadIdx.x;
    __shared__ float strt[64];
    if (threadIdx.x < 64) strt[threadIdx.x] = truths[n * 64 + threadIdx.x];
    __syncthreads();

    float r = 0.0f, contrib = 0.0f;
    if (p < P) {
        u64 k = predkey[(size_t)n * P + p];
        float pt = keyval(k);
        int best = (int)(~(u32)(k & 0xFFFFFFFFULL)) & 15;
        r = fmaxf(pt - 3.0f, 0.0f);
        if (r > 0.0f) {
            const float Bc   = (float)19.085536923187668;
            const float beta = 0.11f;
            float4 pr = *(const float4*)(priors + (size_t)p * 4);
            float tx1 = strt[best * 4],     ty1 = strt[best * 4 + 1];
            float tx2 = strt[best * 4 + 2], ty2 = strt[best * 4 + 3];
            float gcx = ((tx1 + tx2) * 0.5f - pr.x) / (0.1f * pr.z);
            float gcy = ((ty1 + ty2) * 0.5f - pr.y) / (0.1f * pr.w);
            float gw  = flog2((tx2 - tx1) / pr.z) * LN2 / 0.2f;
            float gh  = flog2((ty2 - ty1) / pr.w) * LN2 / 0.2f;
            float4 l  = *(const float4*)(loc + ((size_t)n * P + p) * 4);
            float tgt[4] = {gcx, gcy, gw, gh};
            float lvv[4] = {l.x, l.y, l.z, l.w};
            float s = 0.0f;
            #pragma unroll
            for (int j = 0; j < 4; j++) {
                float diff = fabsf(lvv[j] - tgt[j]);
                float bl;
                if (diff < beta) {
                    bl = 0.5f / Bc * (Bc * diff + 1.0f) * (flog2(1.0f + Bc * diff / beta) * LN2)
                         - 0.5f * diff;
                } else {
                    bl = 1.5f * diff + 1.5f / Bc - 0.5f * beta;
                }
                s += bl;
            }
            contrib = r * s;
        }
    }
    double dl = (double)contrib, dr = (double)r;
    for (int s = 32; s > 0; s >>= 1) { dl += __shfl_down(dl, s, 64); dr += __shfl_down(dr, s, 64); }
    __shared__ double bl_[4], br_[4];
    int wid = threadIdx.x >> 6;
    if ((threadIdx.x & 63) == 0) { bl_[wid] = dl; br_[wid] = dr; }
    __syncthreads();
    if (threadIdx.x == 0) {
        double tl  = bl_[0] + bl_[1] + bl_[2] + bl_[3];
        double tr2 = br_[0] + br_[1] + br_[2] + br_[3];
        atomicAdd(accL, tl);
        atomicAdd(accR, tr2);
    }
}

// ---------- K7: finalize ----------
__global__ void k_final(const double* accC, const double* accL, const double* accR,
                        const unsigned int* posCount, float* out) {
    if (threadIdx.x == 0) {
        unsigned int pc = *posCount;
        double npos = (double)(pc > 0u ? pc : 1u);
        double denom = 4.0 * (*accR);
        out[0] = (float)((*accL) / denom);
        out[1] = (float)((*accC) / npos);
    }
}

extern "C" void kernel_launch(void* const* d_in, const int* in_sizes, int n_in,
                              void* d_out, int out_size, void* d_ws, size_t ws_size,
                              hipStream_t stream) {
    const float* loc    = (const float*)d_in[0];
    const float* conf   = (const float*)d_in[1];
    const float* priors = (const float*)d_in[2];
    const float* truths = (const float*)d_in[3];
    const int*   labels = (const int*)d_in[4];

    int P = in_sizes[2] / 4;                 // 18000
    int N = in_sizes[0] / (P * 4);           // 32
    int NBLK = (P + 63) / 64;                // 282
    // C == 80, O == 16 assumed by kernel tiling

    char* ws = (char*)d_ws;
    double* accC = (double*)ws;
    double* accL = accC + 1;
    double* accR = accC + 2;
    unsigned int* posCount = (unsigned int*)(accC + 3);
    u64* ovkey   = (u64*)(ws + 64);                       // N*P
    u64* predkey = ovkey + (size_t)N * P;                 // N*P
    u64* cand    = predkey + (size_t)N * P;               // N*16*NBLK*15
    float* out = (float*)d_out;

    dim3 blk(256);
    dim3 gridB(NBLK, N);
    dim3 gridL((P + 255) / 256, N);
    size_t mergeLds = (size_t)NBLK * 15 * sizeof(u64);    // 33840 B

    k_zero<<<1, 64, 0, stream>>>(accC, accL, accR, posCount);
    k_reg<<<gridB, blk, 0, stream>>>(loc, priors, truths, ovkey, cand, P, NBLK);
    k_merge_boost<<<N * 16, blk, mergeLds, stream>>>(cand, ovkey, P, NBLK);
    k_conf<<<gridB, blk, 0, stream>>>(conf, priors, truths, labels, ovkey, predkey,
                                      cand, accC, posCount, P, NBLK);
    k_merge_boost<<<N * 16, blk, mergeLds, stream>>>(cand, predkey, P, NBLK);
    k_loss_l<<<gridL, blk, 0, stream>>>(predkey, loc, priors, truths, accL, accR, P);
    k_final<<<1, 1, 0, stream>>>(accC, accL, accR, posCount, out);
}